// Round 3
// baseline (566.118 us; speedup 1.0000x reference)
//
#include <hip/hip_runtime.h>
#include <cstdint>
#include <cstddef>

// ---- problem constants ----
#define BQ   8
#define NP   512
#define GQ   16
#define PP   528      // NP + GQ
#define RT   4224     // BQ * PP
#define CC   91
#define FEATD 12544
#define REPD 1024
#define NH   512      // padded head output cols (455 used: 91 cls + 364 box)
#define NHU  455
#define BETA (1.0f/9.0f)
#define WSC  64.0f    // fp8 weight pre-scale (exact pow2; undone in reduce/loss)

typedef float f32x4 __attribute__((ext_vector_type(4)));
typedef int   v8i  __attribute__((ext_vector_type(8)));
typedef float v16f __attribute__((ext_vector_type(16)));

__device__ __forceinline__ unsigned short f2bf(float f) {
  unsigned int x = __float_as_uint(f);
  unsigned int r = (x + 0x7fffu + ((x >> 16) & 1u)) >> 16;
  return (unsigned short)r;
}
__device__ __forceinline__ float bf2f(unsigned short u) {
  return __uint_as_float((unsigned int)u << 16);
}
__device__ __forceinline__ unsigned char f2fp8(float f) {
  return (unsigned char)(__builtin_amdgcn_cvt_pk_fp8_f32(f, 0.0f, 0, false) & 0xff);
}

// async global->LDS DMA, 16 B per lane; HW writes lane L to base + L*16.
__device__ __forceinline__ void ld_lds16(const void* g, void* l) {
  __builtin_amdgcn_global_load_lds(
      (const __attribute__((address_space(1))) void*)g,
      (__attribute__((address_space(3))) void*)l, 16, 0, 0);
}

// ---- workspace layout (bytes); total ~107 MB (ws >= 230.6 MB proven R2) ----
constexpr size_t O_W1T = 0;
constexpr size_t SZ_W1T = (size_t)FEATD * REPD;             // W1^T fp8 [1024][12544]
constexpr size_t O_W2T = O_W1T + SZ_W1T;
constexpr size_t SZ_W2T = (size_t)REPD * REPD;              // W2^T fp8
constexpr size_t O_WH  = O_W2T + SZ_W2T;
constexpr size_t SZ_WH = (size_t)NH * REPD;                 // [Wcls|Wbox]^T fp8
constexpr size_t O_BH  = O_WH + SZ_WH;
constexpr size_t SZ_BH = (size_t)NH * 4;
constexpr size_t O_X1  = O_BH + SZ_BH;
constexpr size_t SZ_X1 = (size_t)RT * REPD;                 // x1 fp8
constexpr size_t O_X2  = O_X1 + SZ_X1;                      // x2 fp8
constexpr size_t O_LAB = O_X2 + SZ_X1;
constexpr size_t O_TGT = O_LAB + (size_t)RT * 4;
constexpr size_t O_NLL = O_TGT + (size_t)RT * 16;
constexpr size_t O_VC  = O_NLL + (size_t)RT * 4;
constexpr size_t O_SL1 = O_VC + (size_t)RT * 4;
constexpr size_t O_PART = ((O_SL1 + (size_t)RT * 4) + 255) & ~(size_t)255;
constexpr size_t SZ_PART = (size_t)4 * RT * REPD * 2;       // bf16 partials, 34.6 MB max
constexpr size_t O_F8 = O_PART + SZ_PART;                   // fp8 features, 53 MB

// ---- prep: feature fp8-convert + weight transpose-convert(x64) + head + matcher ----
__device__ __forceinline__ void t32(const float* __restrict__ in, unsigned char* __restrict__ out,
                                    int K, int N, int row_off, int out_ld,
                                    int bx, int by, int t, float (*tile)[33]) {
  int tx = t & 31, ty = t >> 5;
  int n0 = bx * 32, k0 = by * 32;
#pragma unroll
  for (int i = 0; i < 4; ++i) {
    int k = k0 + ty + i * 8, n = n0 + tx;
    if (k < K && n < N) tile[ty + i * 8][tx] = in[(size_t)k * N + n];
  }
  __syncthreads();
#pragma unroll
  for (int i = 0; i < 4; ++i) {
    int n = n0 + ty + i * 8, k = k0 + tx;
    if (n < N && k < K) out[(size_t)(n + row_off) * out_ld + k] = f2fp8(tile[tx][ty + i * 8] * WSC);
  }
}

#define NB_CV ((RT * FEATD / 4) / 256)   // 51744
#define NB_W1 ((REPD/32)*(FEATD/32))     // 12544
#define NB_W2 ((REPD/32)*(REPD/32))      // 1024
#define NB_WC (3*(REPD/32))              // 96
#define NB_WB (12*(REPD/32))             // 384
#define NB_HI 230
#define NB_MT 17
#define NB_PREP (NB_CV+NB_W1+NB_W2+NB_WC+NB_WB+NB_HI+NB_MT)

__global__ void prep(const float* __restrict__ feat, unsigned int* __restrict__ feat8,
                     const float* __restrict__ W1, const float* __restrict__ W2,
                     const float* __restrict__ Wcls, const float* __restrict__ Wbox,
                     const float* __restrict__ bcls, const float* __restrict__ bbox,
                     const float* __restrict__ proposals, const float* __restrict__ gt_boxes,
                     const int* __restrict__ gt_labels,
                     unsigned char* __restrict__ W1t, unsigned char* __restrict__ W2t,
                     unsigned char* __restrict__ Wh, float* __restrict__ bh,
                     int* __restrict__ labels, float* __restrict__ tgts) {
  __shared__ float tile[32][33];
  int b = blockIdx.x, t = threadIdx.x;
  if (b < NB_CV) {
    long i = (long)b * 256 + t;
    float4 f = ((const float4*)feat)[i];
    unsigned int r = (unsigned int)__builtin_amdgcn_cvt_pk_fp8_f32(f.x, f.y, 0, false);
    r = (unsigned int)__builtin_amdgcn_cvt_pk_fp8_f32(f.z, f.w, (int)r, true);
    feat8[i] = r;
    return;
  }
  b -= NB_CV;
  if (b < NB_W1) { t32(W1, W1t, FEATD, REPD, 0, FEATD, b % (REPD/32), b / (REPD/32), t, tile); return; }
  b -= NB_W1;
  if (b < NB_W2) { t32(W2, W2t, REPD, REPD, 0, REPD, b % 32, b / 32, t, tile); return; }
  b -= NB_W2;
  if (b < NB_WC) { t32(Wcls, Wh, REPD, CC, 0, REPD, b % 3, b / 3, t, tile); return; }
  b -= NB_WC;
  if (b < NB_WB) { t32(Wbox, Wh, REPD, 4 * CC, CC, REPD, b % 12, b / 12, t, tile); return; }
  b -= NB_WB;
  if (b < NB_HI) {
    int idx = b * 256 + t;
    const int npad = (NH - NHU) * REPD;   // 58368 bytes of fp8 zero
    if (idx < npad) Wh[(size_t)NHU * REPD + idx] = 0;
    else {
      int i2 = idx - npad;
      if (i2 < NH) bh[i2] = (i2 < CC) ? bcls[i2] : (i2 < NHU ? bbox[i2 - CC] : 0.0f);
    }
    return;
  }
  b -= NB_HI;
  // ---- matcher + encode (exact fp32) ----
  int r = b * 256 + t;
  if (r >= RT) return;
  int bi_ = r / PP, p = r % PP;
  float x0, y0, x1, y1;
  if (p < NP) {
    const float* qq = proposals + ((size_t)bi_ * NP + p) * 4;
    x0 = qq[0]; y0 = qq[1]; x1 = qq[2]; y1 = qq[3];
  } else {
    const float* qq = gt_boxes + ((size_t)bi_ * GQ + (p - NP)) * 4;
    x0 = qq[0]; y0 = qq[1]; x1 = qq[2]; y1 = qq[3];
  }
  float ap = (x1 - x0) * (y1 - y0);
  float best = -1.0f; int bg = 0;
#pragma unroll
  for (int g = 0; g < GQ; ++g) {
    const float* gb = gt_boxes + ((size_t)bi_ * GQ + g) * 4;
    float gx0 = gb[0], gy0 = gb[1], gx1 = gb[2], gy1 = gb[3];
    float ag = (gx1 - gx0) * (gy1 - gy0);
    float iw = fmaxf(fminf(gx1, x1) - fmaxf(gx0, x0), 0.0f);
    float ih = fmaxf(fminf(gy1, y1) - fmaxf(gy0, y0), 0.0f);
    float inter = iw * ih;
    float iou = inter / (ag + ap - inter);
    if (iou > best) { best = iou; bg = g; }   // strict > keeps first max (jnp.argmax)
  }
  int lab = gt_labels[bi_ * GQ + bg];
  if (best < 0.5f) lab = 0;    // FG==BG==0.5 -> ignore band empty
  labels[r] = lab;
  const float* gb = gt_boxes + ((size_t)bi_ * GQ + bg) * 4;
  float ew = x1 - x0, eh = y1 - y0;
  float ex = x0 + 0.5f * ew, ey = y0 + 0.5f * eh;
  float gw = gb[2] - gb[0], gh = gb[3] - gb[1];
  float gx = gb[0] + 0.5f * gw, gy = gb[1] + 0.5f * gh;
  tgts[r * 4 + 0] = 10.0f * (gx - ex) / ew;
  tgts[r * 4 + 1] = 10.0f * (gy - ey) / eh;
  tgts[r * 4 + 2] = 5.0f * logf(gw / ew);
  tgts[r * 4 + 3] = 5.0f * logf(gh / eh);
}

// ---- MX-scaled fp8 GEMM: 128x128 tile, BK=128 staging (128-B rows), dbuf ----
// R2 post-mortem: kernel is staging-THROUGHPUT-bound at 10.2 B/cyc/CU
// (828 MB / 131 us = 6.3 TB/s; prefetch null). m97 sustained 22.7 B/cyc/CU
// with 128-B rows (8 segments per 1 KB DMA instr); our 64-B fp8 rows = 16
// segments -> half rate. Fix: stage 128 K-bytes per row per tile (window =
// 8 rows x 128 B), compute TWO 64-K MFMA steps per staged tile. Plus
// per-n-block K-rotation stagger (GEMM1) to break the 8-reader same-address
// lockstep on each XCD's L2. LDS = 2 x (16+16) KB = 64 KB -> 2 blocks/CU.
// Counted vmcnt(8) keeps next tile's 8 DMA loads in flight across barriers.
__global__ __launch_bounds__(256, 2)
void gemm_f8(const unsigned char* __restrict__ A, const unsigned char* __restrict__ Bt,
             unsigned short* __restrict__ P, int M, int Nc, int K, int Kspl,
             int n_nblk, int n_my, int npairs, int stag) {
  __shared__ unsigned char As[2 * 16384];
  __shared__ unsigned char Bs[2 * 16384];

  const int g = blockIdx.x;
  const int xcd = g & 7;
  const int kix = g >> 3;
  const int n  = kix % n_nblk;
  const int pi = kix / n_nblk;
  const int p  = pi * 8 + xcd;
  if (p >= npairs) return;                 // uniform dummy exit, before any barrier
  const int y  = p % n_my;
  const int kz = p / n_my;
  const int m0 = y * 128, n0 = n * 128;

  const int tid = threadIdx.x;
  const int w = tid >> 6, L = tid & 63;
  const int l31 = L & 31, h = L >> 5;
  const int wr = (w >> 1) * 64, wc = (w & 1) * 64;
  const size_t kbase = (size_t)kz * Kspl;

  // staging: window = 8 rows x 128 B (1 KB / DMA instr, 8 segments).
  // lane L fetches global (row = L&7, kchunk = L>>3); HW writes LDS slot
  // L*16 -> window layout byte = kchunk*128 + row*16.
  const int srow = L & 7, schk = (L >> 3) * 16;
  const long K8 = (long)8 * K;
  const unsigned char* gAr = A  + (size_t)(m0 + w * 32 + srow) * K + kbase + schk;
  const unsigned char* gBr = Bt + (size_t)(n0 + w * 32 + srow) * K + kbase + schk;
  const unsigned char* gA0 = gAr;            const unsigned char* gB0 = gBr;
  const unsigned char* gA1 = gAr + K8;       const unsigned char* gB1 = gBr + K8;
  const unsigned char* gA2 = gAr + 2 * K8;   const unsigned char* gB2 = gBr + 2 * K8;
  const unsigned char* gA3 = gAr + 3 * K8;   const unsigned char* gB3 = gBr + 3 * K8;
  const int lo0 = w * 4096;                  // wave w owns windows 4w..4w+3

#define STAGE(kb2, bufo) do {                                   \
    const int _ko = (kb2) * 128;                                \
    ld_lds16(gA0 + _ko, &As[(bufo) + lo0]);                     \
    ld_lds16(gA1 + _ko, &As[(bufo) + lo0 + 1024]);              \
    ld_lds16(gA2 + _ko, &As[(bufo) + lo0 + 2048]);              \
    ld_lds16(gA3 + _ko, &As[(bufo) + lo0 + 3072]);              \
    ld_lds16(gB0 + _ko, &Bs[(bufo) + lo0]);                     \
    ld_lds16(gB1 + _ko, &Bs[(bufo) + lo0 + 1024]);              \
    ld_lds16(gB2 + _ko, &Bs[(bufo) + lo0 + 2048]);              \
    ld_lds16(gB3 + _ko, &Bs[(bufo) + lo0 + 3072]);              \
  } while (0)

  // fragment base: row ra, k-half h -> (ra>>3)*1024 + (ra&7)*16 + h*256;
  // MFMA step s adds s*512; the two b128 are at +0 and +128.
  int aoff[2], boff[2];
#pragma unroll
  for (int i = 0; i < 2; ++i) {
    int ra = wr + i * 32 + l31;
    aoff[i] = (ra >> 3) * 1024 + (ra & 7) * 16 + h * 256;
    int rb = wc + i * 32 + l31;
    boff[i] = (rb >> 3) * 1024 + (rb & 7) * 16 + h * 256;
  }

  const int nk2 = Kspl >> 7;
  int kb2 = n * stag;                 // stagger start (decorrelate same-A readers)
  STAGE(kb2, 0);                      // prologue: tile kb2 -> buffer 0

  v16f acc[2][2] = {};
  int cur = 0;
  for (int t = 0; t < nk2; ++t) {
    const int cb = cur << 14;
    const int nb = cb ^ 16384;
    int kn = kb2 + 1; if (kn == nk2) kn = 0;
    if (t + 1 < nk2) {
      STAGE(kn, nb);                  // issue next tile's 8 DMA (stay in flight)
      asm volatile("s_waitcnt vmcnt(8)" ::: "memory");  // current tile's 8 done
    } else {
      asm volatile("s_waitcnt vmcnt(0)" ::: "memory");
    }
    __builtin_amdgcn_sched_barrier(0);
    __builtin_amdgcn_s_barrier();     // tile staged for all waves

#pragma unroll
    for (int s = 0; s < 2; ++s) {
      v8i a[2], b[2];
#pragma unroll
      for (int i = 0; i < 2; ++i) {
        int4 alo = *(const int4*)&As[cb + aoff[i] + s * 512];
        int4 ahi = *(const int4*)&As[cb + aoff[i] + s * 512 + 128];
        a[i] = (v8i){alo.x, alo.y, alo.z, alo.w, ahi.x, ahi.y, ahi.z, ahi.w};
        int4 blo = *(const int4*)&Bs[cb + boff[i] + s * 512];
        int4 bhi = *(const int4*)&Bs[cb + boff[i] + s * 512 + 128];
        b[i] = (v8i){blo.x, blo.y, blo.z, blo.w, bhi.x, bhi.y, bhi.z, bhi.w};
      }
#pragma unroll
      for (int i = 0; i < 2; ++i)
#pragma unroll
        for (int j = 0; j < 2; ++j)
          acc[i][j] = __builtin_amdgcn_mfma_scale_f32_32x32x64_f8f6f4(
              a[i], b[j], acc[i][j], 0, 0, 0, 127, 0, 127);  // fp8/fp8, scales=2^0
    }

    asm volatile("s_waitcnt lgkmcnt(0)" ::: "memory");  // wave done reading cb
    __builtin_amdgcn_sched_barrier(0);
    __builtin_amdgcn_s_barrier();     // all waves done -> cb reusable
    cur ^= 1;
    kb2 = kn;
  }
#undef STAGE

  // epilogue: 32x32 C/D layout col=l&31, row=(reg&3)+8*(reg>>2)+4*(l>>5) -> bf16
  unsigned short* Pz = P + (size_t)kz * M * Nc;
#pragma unroll
  for (int i = 0; i < 2; ++i) {
#pragma unroll
    for (int j = 0; j < 2; ++j) {
      int colb = n0 + wc + j * 32 + l31;
#pragma unroll
      for (int r = 0; r < 16; ++r) {
        int row = m0 + wr + i * 32 + (r & 3) + 8 * (r >> 2) + 4 * h;
        Pz[(size_t)row * Nc + colb] = f2bf(acc[i][j][r]);
      }
    }
  }
}

// ---- split-K reduce (bf16 partials) + 1/WSC + bias + ReLU -> fp8 out ----
template <int S>
__global__ void reduce_fp8k(const unsigned short* __restrict__ P, const float* __restrict__ bias,
                            unsigned int* __restrict__ outp, long MN4, int nc4) {
  long i = (long)blockIdx.x * blockDim.x + threadIdx.x;
  long stride = (long)gridDim.x * blockDim.x;
  const ushort4* P4 = (const ushort4*)P;
  const float4* B4 = (const float4*)bias;
  for (; i < MN4; i += stride) {
    float vx = 0, vy = 0, vz = 0, vw = 0;
#pragma unroll
    for (int s = 0; s < S; ++s) {
      ushort4 u = P4[s * MN4 + i];
      vx += bf2f(u.x); vy += bf2f(u.y); vz += bf2f(u.z); vw += bf2f(u.w);
    }
    float4 b = B4[i % nc4];
    vx = fmaxf(vx * (1.0f / WSC) + b.x, 0.0f);
    vy = fmaxf(vy * (1.0f / WSC) + b.y, 0.0f);
    vz = fmaxf(vz * (1.0f / WSC) + b.z, 0.0f);
    vw = fmaxf(vw * (1.0f / WSC) + b.w, 0.0f);
    unsigned int r = (unsigned int)__builtin_amdgcn_cvt_pk_fp8_f32(vx, vy, 0, false);
    r = (unsigned int)__builtin_amdgcn_cvt_pk_fp8_f32(vz, vw, (int)r, true);
    outp[i] = r;
  }
}

// ---- per-row loss, reading GEMM3's 4 bf16 split-K slices + bias directly ----
__global__ void loss_row(const unsigned short* __restrict__ P, const float* __restrict__ bh,
                         const int* __restrict__ labels, const float* __restrict__ tgts,
                         float* __restrict__ nll_v, float* __restrict__ vc_v,
                         float* __restrict__ sl1_v) {
  int r = blockIdx.x;
  int l = threadIdx.x;
  const size_t SL = (size_t)RT * NH;
  const unsigned short* p0 = P + (size_t)r * NH;
#define COLV(c) ((bf2f(p0[(c)]) + bf2f(p0[SL + (c)]) + bf2f(p0[2 * SL + (c)]) + \
                  bf2f(p0[3 * SL + (c)])) * (1.0f / WSC) + bh[(c)])
  float v1 = COLV(l);
  float v2 = (l < CC - 64) ? COLV(64 + l) : -3.4e38f;
  float m = fmaxf(v1, v2);
#pragma unroll
  for (int o = 32; o; o >>= 1) m = fmaxf(m, __shfl_xor(m, o));
  float e = __expf(v1 - m) + ((l < CC - 64) ? __expf(v2 - m) : 0.0f);
#pragma unroll
  for (int o = 32; o; o >>= 1) e += __shfl_xor(e, o);
  if (l == 0) {
    float lse = m + __logf(e);
    int lab = labels[r];
    int sl = lab < 0 ? 0 : (lab > CC - 1 ? CC - 1 : lab);
    float valid = (lab >= 0) ? 1.0f : 0.0f;
    nll_v[r] = (lse - COLV(sl)) * valid;
    vc_v[r] = valid;
    float s = 0.0f;
#pragma unroll
    for (int d = 0; d < 4; ++d) {
      float pd = COLV(CC + sl * 4 + d);
      float ad = fabsf(pd - tgts[r * 4 + d]);
      s += (ad < BETA) ? 0.5f * ad * ad / BETA : ad - 0.5f * BETA;
    }
    sl1_v[r] = (lab > 0) ? s : 0.0f;
  }
#undef COLV
}

// ---- deterministic final reduce ----
__global__ void reduce_final(const float* __restrict__ nll_v, const float* __restrict__ vc_v,
                             const float* __restrict__ sl1_v, float* __restrict__ out) {
  __shared__ float s1[256], s2[256], s3[256];
  int t = threadIdx.x;
  float a = 0, b = 0, c = 0;
  for (int i = t; i < RT; i += 256) { a += nll_v[i]; b += vc_v[i]; c += sl1_v[i]; }
  s1[t] = a; s2[t] = b; s3[t] = c;
  __syncthreads();
  for (int o = 128; o; o >>= 1) {
    if (t < o) { s1[t] += s1[t + o]; s2[t] += s2[t + o]; s3[t] += s3[t + o]; }
    __syncthreads();
  }
  if (t == 0) {
    out[0] = s1[0] / fmaxf(s2[0], 1.0f);
    out[1] = s3[0] / (float)RT;
  }
}

extern "C" void kernel_launch(void* const* d_in, const int* in_sizes, int n_in,
                              void* d_out, int out_size, void* d_ws, size_t ws_size,
                              hipStream_t stream) {
  const float* proposals = (const float*)d_in[0];
  const float* gt_boxes  = (const float*)d_in[1];
  const float* features  = (const float*)d_in[2];
  const float* W1   = (const float*)d_in[3];
  const float* b1   = (const float*)d_in[4];
  const float* W2   = (const float*)d_in[5];
  const float* b2   = (const float*)d_in[6];
  const float* Wcls = (const float*)d_in[7];
  const float* bcls = (const float*)d_in[8];
  const float* Wbox = (const float*)d_in[9];
  const float* bbox = (const float*)d_in[10];
  const int* gt_labels = (const int*)d_in[11];
  float* out = (float*)d_out;

  char* ws = (char*)d_ws;
  unsigned char* W1t = (unsigned char*)(ws + O_W1T);
  unsigned char* W2t = (unsigned char*)(ws + O_W2T);
  unsigned char* Wh  = (unsigned char*)(ws + O_WH);
  float* bh          = (float*)(ws + O_BH);
  unsigned char* x1  = (unsigned char*)(ws + O_X1);
  unsigned char* x2  = (unsigned char*)(ws + O_X2);
  int* labels        = (int*)(ws + O_LAB);
  float* tgts        = (float*)(ws + O_TGT);
  float* nll_v       = (float*)(ws + O_NLL);
  float* vc_v        = (float*)(ws + O_VC);
  float* sl1_v       = (float*)(ws + O_SL1);
  unsigned short* part = (unsigned short*)(ws + O_PART);
  unsigned char* feat8 = (unsigned char*)(ws + O_F8);

  // 1. prep: feature fp8 convert + weight transpose-convert(x64) + head + matcher
  prep<<<NB_PREP, 256, 0, stream>>>(features, (unsigned int*)feat8, W1, W2, Wcls, Wbox,
                                    bcls, bbox, proposals, gt_boxes, gt_labels,
                                    W1t, W2t, Wh, bh, labels, tgts);

  // 2. GEMM1: split-2 (Kspl=6272=49*128), pairs=33*2=66, 8 n-blocks
  //    grid 8*8*ceil(66/8)=576; stagger = 49/8 = 6 K-tiles per n-block
  gemm_f8<<<576, 256, 0, stream>>>(feat8, W1t, part, RT, REPD, FEATD, FEATD / 2,
                                   8, 33, 66, 6);
  reduce_fp8k<2><<<2048, 256, 0, stream>>>(part, b1, (unsigned int*)x1,
                                           (long)RT * REPD / 4, REPD / 4);

  // 3. GEMM2: split-2 (Kspl=512, nk2=4), pairs=66 -> grid 576
  gemm_f8<<<576, 256, 0, stream>>>(x1, W2t, part, RT, REPD, REPD, REPD / 2,
                                   8, 33, 66, 0);
  reduce_fp8k<2><<<2048, 256, 0, stream>>>(part, b2, (unsigned int*)x2,
                                           (long)RT * REPD / 4, REPD / 4);

  // 4. GEMM3: split-4 (Kspl=256, nk2=2), Nc=512 (4 n-blocks), pairs=132
  //    grid 8*4*ceil(132/8)=544
  gemm_f8<<<544, 256, 0, stream>>>(x2, Wh, part, RT, NH, REPD, REPD / 4,
                                   4, 33, 132, 0);

  // 5. losses (loss_row folds GEMM3's 4-slice reduce + bias + 1/WSC)
  loss_row<<<RT, 64, 0, stream>>>(part, bh, labels, tgts, nll_v, vc_v, sl1_v);
  reduce_final<<<1, 256, 0, stream>>>(nll_v, vc_v, sl1_v, out);
}

// Round 4
// 485.940 us; speedup vs baseline: 1.1650x; 1.1650x over previous
//
#include <hip/hip_runtime.h>
#include <cstdint>
#include <cstddef>

// ---- problem constants ----
#define BQ   8
#define NP   512
#define GQ   16
#define PP   528      // NP + GQ
#define RT   4224     // BQ * PP
#define CC   91
#define FEATD 12544
#define REPD 1024
#define NH   512      // padded head output cols (455 used: 91 cls + 364 box)
#define NHU  455
#define BETA (1.0f/9.0f)
#define WSC  64.0f    // fp8 weight pre-scale (exact pow2; undone in reduce/loss)

typedef float f32x4 __attribute__((ext_vector_type(4)));
typedef int   v8i  __attribute__((ext_vector_type(8)));
typedef float v16f __attribute__((ext_vector_type(16)));

__device__ __forceinline__ unsigned short f2bf(float f) {
  unsigned int x = __float_as_uint(f);
  unsigned int r = (x + 0x7fffu + ((x >> 16) & 1u)) >> 16;
  return (unsigned short)r;
}
__device__ __forceinline__ float bf2f(unsigned short u) {
  return __uint_as_float((unsigned int)u << 16);
}
__device__ __forceinline__ unsigned char f2fp8(float f) {
  return (unsigned char)(__builtin_amdgcn_cvt_pk_fp8_f32(f, 0.0f, 0, false) & 0xff);
}

// async global->LDS DMA, 16 B per lane; HW writes lane L to base + L*16.
__device__ __forceinline__ void ld_lds16(const void* g, void* l) {
  __builtin_amdgcn_global_load_lds(
      (const __attribute__((address_space(1))) void*)g,
      (__attribute__((address_space(3))) void*)l, 16, 0, 0);
}

// ---- tile-image layout --------------------------------------------------
// All GEMM operands are stored pre-tiled in global memory so that staging is
// PURE SEQUENTIAL global_load_lds (1024 contiguous bytes / instr = 8 full
// 128-B L2 lines) and LDS fragment reads are dense (zero bank conflicts).
// Image: 128-row x 64-kbyte tile = 8192 B, tiles ordered [rowblk][ktile].
// Within a tile: region w = (row>>5)&3 (2048 B), then [kc=(kb>>4)&3][r=row&31][16B].
// Fragment read (32 lanes, kc fixed): contiguous 512 B -> conflict-free.
__device__ __forceinline__ size_t img_off(int row, int kb, int KT) {
  return (size_t)((row >> 7) * KT + (kb >> 6)) * 8192
       + (size_t)((((row >> 5) & 3) << 11) + (((kb >> 4) & 3) << 9)
                  + ((row & 31) << 4) + (kb & 15));
}

// ---- workspace layout (bytes); total ~107 MB ----
constexpr size_t O_W1T = 0;
constexpr size_t SZ_W1T = (size_t)FEATD * REPD;             // W1^T fp8 image
constexpr size_t O_W2T = O_W1T + SZ_W1T;
constexpr size_t SZ_W2T = (size_t)REPD * REPD;              // W2^T fp8 image
constexpr size_t O_WH  = O_W2T + SZ_W2T;
constexpr size_t SZ_WH = (size_t)NH * REPD;                 // [Wcls|Wbox]^T fp8 image
constexpr size_t O_BH  = O_WH + SZ_WH;
constexpr size_t SZ_BH = (size_t)NH * 4;
constexpr size_t O_X1  = O_BH + SZ_BH;
constexpr size_t SZ_X1 = (size_t)RT * REPD;                 // x1 fp8 image
constexpr size_t O_X2  = O_X1 + SZ_X1;                      // x2 fp8 image
constexpr size_t O_LAB = O_X2 + SZ_X1;
constexpr size_t O_TGT = O_LAB + (size_t)RT * 4;
constexpr size_t O_NLL = O_TGT + (size_t)RT * 16;
constexpr size_t O_VC  = O_NLL + (size_t)RT * 4;
constexpr size_t O_SL1 = O_VC + (size_t)RT * 4;
constexpr size_t O_PART = ((O_SL1 + (size_t)RT * 4) + 255) & ~(size_t)255;
constexpr size_t SZ_PART = (size_t)4 * RT * REPD * 2;       // bf16 partials
constexpr size_t O_F8 = O_PART + SZ_PART;                   // fp8 feature image, 53 MB

// ---- prep ----
// CV: feature fp32 -> fp8 tile image (LDS transpose per 128x64 tile).
// t32: weight transpose-convert(x64) -> tile image.
__device__ __forceinline__ void t32(const float* __restrict__ in, unsigned char* __restrict__ out,
                                    int K, int N, int row_off, int KT,
                                    int bx, int by, int t, float (*tile)[33]) {
  int tx = t & 31, ty = t >> 5;
  int n0 = bx * 32, k0 = by * 32;
#pragma unroll
  for (int i = 0; i < 4; ++i) {
    int k = k0 + ty + i * 8, n = n0 + tx;
    if (k < K && n < N) tile[ty + i * 8][tx] = in[(size_t)k * N + n];
  }
  __syncthreads();
#pragma unroll
  for (int i = 0; i < 4; ++i) {
    int n = n0 + ty + i * 8, k = k0 + tx;
    if (n < N && k < K)
      out[img_off(n + row_off, k, KT)] = f2fp8(tile[tx][ty + i * 8] * WSC);
  }
}

#define NB_CV ((RT/128)*(FEATD/64))      // 33*196 = 6468 tile blocks
#define NB_W1 ((REPD/32)*(FEATD/32))     // 12544
#define NB_W2 ((REPD/32)*(REPD/32))      // 1024
#define NB_WC (3*(REPD/32))              // 96
#define NB_WB (12*(REPD/32))             // 384
#define NB_HI 230
#define NB_MT 17
#define NB_PREP (NB_CV+NB_W1+NB_W2+NB_WC+NB_WB+NB_HI+NB_MT)

__global__ void prep(const float* __restrict__ feat, unsigned char* __restrict__ feat8,
                     const float* __restrict__ W1, const float* __restrict__ W2,
                     const float* __restrict__ Wcls, const float* __restrict__ Wbox,
                     const float* __restrict__ bcls, const float* __restrict__ bbox,
                     const float* __restrict__ proposals, const float* __restrict__ gt_boxes,
                     const int* __restrict__ gt_labels,
                     unsigned char* __restrict__ W1t, unsigned char* __restrict__ W2t,
                     unsigned char* __restrict__ Wh, float* __restrict__ bh,
                     int* __restrict__ labels, float* __restrict__ tgts) {
  __shared__ float tile[32][33];
  __shared__ unsigned char cvbuf[8192];
  int b = blockIdx.x, t = threadIdx.x;
  if (b < NB_CV) {
    // one 128-row x 64-kbyte tile image; coalesced fp32 reads, linear image write
    int yb = b / (FEATD / 64), kt = b % (FEATD / 64);
    const float* src = feat + (size_t)(yb * 128) * FEATD + kt * 64;
#pragma unroll
    for (int p = 0; p < 8; ++p) {
      int lr = p * 16 + (t >> 4);          // local row 0..127
      int kb = (t & 15) * 4;               // k-byte (== float col) 0..63
      float4 f = *(const float4*)(src + (size_t)lr * FEATD + kb);
      unsigned int r = (unsigned int)__builtin_amdgcn_cvt_pk_fp8_f32(f.x, f.y, 0, false);
      r = (unsigned int)__builtin_amdgcn_cvt_pk_fp8_f32(f.z, f.w, (int)r, true);
      int o = (((lr >> 5) & 3) << 11) + (((kb >> 4) & 3) << 9) + ((lr & 31) << 4) + (kb & 15);
      *(unsigned int*)&cvbuf[o] = r;
    }
    __syncthreads();
    int4* dst = (int4*)(feat8 + (size_t)b * 8192);
    const int4* sb = (const int4*)cvbuf;
    dst[t] = sb[t];
    dst[256 + t] = sb[256 + t];
    return;
  }
  b -= NB_CV;
  if (b < NB_W1) { t32(W1, W1t, FEATD, REPD, 0, FEATD/64, b % (REPD/32), b / (REPD/32), t, tile); return; }
  b -= NB_W1;
  if (b < NB_W2) { t32(W2, W2t, REPD, REPD, 0, REPD/64, b % 32, b / 32, t, tile); return; }
  b -= NB_W2;
  if (b < NB_WC) { t32(Wcls, Wh, REPD, CC, 0, REPD/64, b % 3, b / 3, t, tile); return; }
  b -= NB_WC;
  if (b < NB_WB) { t32(Wbox, Wh, REPD, 4 * CC, CC, REPD/64, b % 12, b / 12, t, tile); return; }
  b -= NB_WB;
  if (b < NB_HI) {
    int idx = b * 256 + t;
    const int npad = (NH - NHU) * REPD;   // 58368 fp8 zeros (rows 455..511)
    if (idx < npad) {
      int row = NHU + (idx >> 10), k = idx & 1023;
      Wh[img_off(row, k, REPD/64)] = 0;
    } else {
      int i2 = idx - npad;
      if (i2 < NH) bh[i2] = (i2 < CC) ? bcls[i2] : (i2 < NHU ? bbox[i2 - CC] : 0.0f);
    }
    return;
  }
  b -= NB_HI;
  // ---- matcher + encode (exact fp32) ----
  int r = b * 256 + t;
  if (r >= RT) return;
  int bi_ = r / PP, p = r % PP;
  float x0, y0, x1, y1;
  if (p < NP) {
    const float* qq = proposals + ((size_t)bi_ * NP + p) * 4;
    x0 = qq[0]; y0 = qq[1]; x1 = qq[2]; y1 = qq[3];
  } else {
    const float* qq = gt_boxes + ((size_t)bi_ * GQ + (p - NP)) * 4;
    x0 = qq[0]; y0 = qq[1]; x1 = qq[2]; y1 = qq[3];
  }
  float ap = (x1 - x0) * (y1 - y0);
  float best = -1.0f; int bg = 0;
#pragma unroll
  for (int g = 0; g < GQ; ++g) {
    const float* gb = gt_boxes + ((size_t)bi_ * GQ + g) * 4;
    float gx0 = gb[0], gy0 = gb[1], gx1 = gb[2], gy1 = gb[3];
    float ag = (gx1 - gx0) * (gy1 - gy0);
    float iw = fmaxf(fminf(gx1, x1) - fmaxf(gx0, x0), 0.0f);
    float ih = fmaxf(fminf(gy1, y1) - fmaxf(gy0, y0), 0.0f);
    float inter = iw * ih;
    float iou = inter / (ag + ap - inter);
    if (iou > best) { best = iou; bg = g; }   // strict > keeps first max (jnp.argmax)
  }
  int lab = gt_labels[bi_ * GQ + bg];
  if (best < 0.5f) lab = 0;    // FG==BG==0.5 -> ignore band empty
  labels[r] = lab;
  const float* gb = gt_boxes + ((size_t)bi_ * GQ + bg) * 4;
  float ew = x1 - x0, eh = y1 - y0;
  float ex = x0 + 0.5f * ew, ey = y0 + 0.5f * eh;
  float gw = gb[2] - gb[0], gh = gb[3] - gb[1];
  float gx = gb[0] + 0.5f * gw, gy = gb[1] + 0.5f * gh;
  tgts[r * 4 + 0] = 10.0f * (gx - ex) / ew;
  tgts[r * 4 + 1] = 10.0f * (gy - ey) / eh;
  tgts[r * 4 + 2] = 5.0f * logf(gw / ew);
  tgts[r * 4 + 3] = 5.0f * logf(gh / eh);
}

// ---- MX-scaled fp8 GEMM on tile images: 128x128, BK=64, dbuf, vmcnt(4) ----
// Staging = linear global_load_lds of the pre-tiled image (1024 contiguous
// bytes/instr, sequential across iters). Fragment ds_read_b128: two dense
// 512-B spans -> zero bank conflicts. XCD pair-mapping (no stagger): 8
// n-blocks sharing one A-slice run lockstep on ONE XCD -> A L2-dedup'd.
__global__ __launch_bounds__(256, 4)
void gemm_f8(const unsigned char* __restrict__ Aimg, const unsigned char* __restrict__ Bimg,
             unsigned short* __restrict__ P, int M, int Nc, int KT, int nkt,
             int n_nblk, int n_my, int npairs) {
  __shared__ unsigned char As[2 * 8192];
  __shared__ unsigned char Bs[2 * 8192];

  const int g = blockIdx.x;
  const int xcd = g & 7;
  const int kix = g >> 3;
  const int n  = kix % n_nblk;
  const int pi = kix / n_nblk;
  const int p  = pi * 8 + xcd;
  if (p >= npairs) return;                 // uniform dummy exit, before any barrier
  const int y  = p % n_my;
  const int kz = p / n_my;
  const int m0 = y * 128, n0 = n * 128;

  const int tid = threadIdx.x;
  const int w = tid >> 6, L = tid & 63;
  const int l31 = L & 31, h = L >> 5;
  const int wr = (w >> 1) * 64, wc = (w & 1) * 64;

  const int kt0 = kz * nkt;
  const unsigned char* gA = Aimg + ((size_t)y * KT + kt0) * 8192 + w * 2048 + L * 16;
  const unsigned char* gB = Bimg + ((size_t)n * KT + kt0) * 8192 + w * 2048 + L * 16;
  const int lw = w * 2048;                 // wave w stages region w

#define STAGE(it, bufo) do {                                    \
    const size_t _go = (size_t)(it) * 8192;                     \
    ld_lds16(gA + _go,        &As[(bufo) + lw]);                \
    ld_lds16(gA + _go + 1024, &As[(bufo) + lw + 1024]);         \
    ld_lds16(gB + _go,        &Bs[(bufo) + lw]);                \
    ld_lds16(gB + _go + 1024, &Bs[(bufo) + lw + 1024]);         \
  } while (0)

  // fragment base: A rows wr+i*32+l31 -> region (wr>>5)+i; chunk 2h at h*1024,
  // chunk 2h+1 at +512. 32 lanes same kc = contiguous 512 B (conflict-free).
  int aoff[2], boff[2];
#pragma unroll
  for (int i = 0; i < 2; ++i) {
    aoff[i] = (((w >> 1) * 2 + i) << 11) + (h << 10) + (l31 << 4);
    boff[i] = (((w & 1) * 2 + i) << 11) + (h << 10) + (l31 << 4);
  }

  STAGE(0, 0);                              // prologue: tile 0 -> buffer 0

  v16f acc[2][2] = {};
  int cur = 0;
  for (int it = 0; it < nkt; ++it) {
    const int cb = cur << 13;
    if (it + 1 < nkt) {
      STAGE(it + 1, cb ^ 8192);             // next tile's 4 DMA stay in flight
      asm volatile("s_waitcnt vmcnt(4)" ::: "memory");
    } else {
      asm volatile("s_waitcnt vmcnt(0)" ::: "memory");
    }
    __builtin_amdgcn_sched_barrier(0);
    __builtin_amdgcn_s_barrier();           // tile staged for all waves

    v8i a[2], b[2];
#pragma unroll
    for (int i = 0; i < 2; ++i) {
      int4 alo = *(const int4*)&As[cb + aoff[i]];
      int4 ahi = *(const int4*)&As[cb + aoff[i] + 512];
      a[i] = (v8i){alo.x, alo.y, alo.z, alo.w, ahi.x, ahi.y, ahi.z, ahi.w};
      int4 blo = *(const int4*)&Bs[cb + boff[i]];
      int4 bhi = *(const int4*)&Bs[cb + boff[i] + 512];
      b[i] = (v8i){blo.x, blo.y, blo.z, blo.w, bhi.x, bhi.y, bhi.z, bhi.w};
    }
#pragma unroll
    for (int i = 0; i < 2; ++i)
#pragma unroll
      for (int j = 0; j < 2; ++j)
        acc[i][j] = __builtin_amdgcn_mfma_scale_f32_32x32x64_f8f6f4(
            a[i], b[j], acc[i][j], 0, 0, 0, 127, 0, 127);  // fp8/fp8, scales=2^0

    asm volatile("s_waitcnt lgkmcnt(0)" ::: "memory");
    __builtin_amdgcn_sched_barrier(0);
    __builtin_amdgcn_s_barrier();           // all waves done -> buffer reusable
    cur ^= 1;
  }
#undef STAGE

  // epilogue: 32x32 C/D layout col=l&31, row=(reg&3)+8*(reg>>2)+4*(l>>5) -> bf16
  unsigned short* Pz = P + (size_t)kz * M * Nc;
#pragma unroll
  for (int i = 0; i < 2; ++i) {
#pragma unroll
    for (int j = 0; j < 2; ++j) {
      int colb = n0 + wc + j * 32 + l31;
#pragma unroll
      for (int r = 0; r < 16; ++r) {
        int row = m0 + wr + i * 32 + (r & 3) + 8 * (r >> 2) + 4 * h;
        Pz[(size_t)row * Nc + colb] = f2bf(acc[i][j][r]);
      }
    }
  }
}

// ---- split-K reduce (bf16 partials) + 1/WSC + bias + ReLU -> fp8 image ----
template <int S>
__global__ void reduce_fp8k(const unsigned short* __restrict__ P, const float* __restrict__ bias,
                            unsigned int* __restrict__ outp, long MN4, int nc4) {
  long i = (long)blockIdx.x * blockDim.x + threadIdx.x;
  long stride = (long)gridDim.x * blockDim.x;
  const ushort4* P4 = (const ushort4*)P;
  const float4* B4 = (const float4*)bias;
  for (; i < MN4; i += stride) {
    float vx = 0, vy = 0, vz = 0, vw = 0;
#pragma unroll
    for (int s = 0; s < S; ++s) {
      ushort4 u = P4[s * MN4 + i];
      vx += bf2f(u.x); vy += bf2f(u.y); vz += bf2f(u.z); vw += bf2f(u.w);
    }
    float4 b = B4[i & (nc4 - 1)];
    vx = fmaxf(vx * (1.0f / WSC) + b.x, 0.0f);
    vy = fmaxf(vy * (1.0f / WSC) + b.y, 0.0f);
    vz = fmaxf(vz * (1.0f / WSC) + b.z, 0.0f);
    vw = fmaxf(vw * (1.0f / WSC) + b.w, 0.0f);
    unsigned int r = (unsigned int)__builtin_amdgcn_cvt_pk_fp8_f32(vx, vy, 0, false);
    r = (unsigned int)__builtin_amdgcn_cvt_pk_fp8_f32(vz, vw, (int)r, true);
    // store into tile-image position (row rr, kbyte kb), KT = REPD/64 = 16
    int rr = (int)(i >> 8);
    int kb = ((int)i & 255) * 4;
    outp[img_off(rr, kb, REPD / 64) >> 2] = r;
  }
}

// ---- per-row loss, reading GEMM3's 4 bf16 split-K slices + bias directly ----
__global__ void loss_row(const unsigned short* __restrict__ P, const float* __restrict__ bh,
                         const int* __restrict__ labels, const float* __restrict__ tgts,
                         float* __restrict__ nll_v, float* __restrict__ vc_v,
                         float* __restrict__ sl1_v) {
  int r = blockIdx.x;
  int l = threadIdx.x;
  const size_t SL = (size_t)RT * NH;
  const unsigned short* p0 = P + (size_t)r * NH;
#define COLV(c) ((bf2f(p0[(c)]) + bf2f(p0[SL + (c)]) + bf2f(p0[2 * SL + (c)]) + \
                  bf2f(p0[3 * SL + (c)])) * (1.0f / WSC) + bh[(c)])
  float v1 = COLV(l);
  float v2 = (l < CC - 64) ? COLV(64 + l) : -3.4e38f;
  float m = fmaxf(v1, v2);
#pragma unroll
  for (int o = 32; o; o >>= 1) m = fmaxf(m, __shfl_xor(m, o));
  float e = __expf(v1 - m) + ((l < CC - 64) ? __expf(v2 - m) : 0.0f);
#pragma unroll
  for (int o = 32; o; o >>= 1) e += __shfl_xor(e, o);
  if (l == 0) {
    float lse = m + __logf(e);
    int lab = labels[r];
    int sl = lab < 0 ? 0 : (lab > CC - 1 ? CC - 1 : lab);
    float valid = (lab >= 0) ? 1.0f : 0.0f;
    nll_v[r] = (lse - COLV(sl)) * valid;
    vc_v[r] = valid;
    float s = 0.0f;
#pragma unroll
    for (int d = 0; d < 4; ++d) {
      float pd = COLV(CC + sl * 4 + d);
      float ad = fabsf(pd - tgts[r * 4 + d]);
      s += (ad < BETA) ? 0.5f * ad * ad / BETA : ad - 0.5f * BETA;
    }
    sl1_v[r] = (lab > 0) ? s : 0.0f;
  }
#undef COLV
}

// ---- deterministic final reduce ----
__global__ void reduce_final(const float* __restrict__ nll_v, const float* __restrict__ vc_v,
                             const float* __restrict__ sl1_v, float* __restrict__ out) {
  __shared__ float s1[256], s2[256], s3[256];
  int t = threadIdx.x;
  float a = 0, b = 0, c = 0;
  for (int i = t; i < RT; i += 256) { a += nll_v[i]; b += vc_v[i]; c += sl1_v[i]; }
  s1[t] = a; s2[t] = b; s3[t] = c;
  __syncthreads();
  for (int o = 128; o; o >>= 1) {
    if (t < o) { s1[t] += s1[t + o]; s2[t] += s2[t + o]; s3[t] += s3[t + o]; }
    __syncthreads();
  }
  if (t == 0) {
    out[0] = s1[0] / fmaxf(s2[0], 1.0f);
    out[1] = s3[0] / (float)RT;
  }
}

extern "C" void kernel_launch(void* const* d_in, const int* in_sizes, int n_in,
                              void* d_out, int out_size, void* d_ws, size_t ws_size,
                              hipStream_t stream) {
  const float* proposals = (const float*)d_in[0];
  const float* gt_boxes  = (const float*)d_in[1];
  const float* features  = (const float*)d_in[2];
  const float* W1   = (const float*)d_in[3];
  const float* b1   = (const float*)d_in[4];
  const float* W2   = (const float*)d_in[5];
  const float* b2   = (const float*)d_in[6];
  const float* Wcls = (const float*)d_in[7];
  const float* bcls = (const float*)d_in[8];
  const float* Wbox = (const float*)d_in[9];
  const float* bbox = (const float*)d_in[10];
  const int* gt_labels = (const int*)d_in[11];
  float* out = (float*)d_out;

  char* ws = (char*)d_ws;
  unsigned char* W1t = (unsigned char*)(ws + O_W1T);
  unsigned char* W2t = (unsigned char*)(ws + O_W2T);
  unsigned char* Wh  = (unsigned char*)(ws + O_WH);
  float* bh          = (float*)(ws + O_BH);
  unsigned char* x1  = (unsigned char*)(ws + O_X1);
  unsigned char* x2  = (unsigned char*)(ws + O_X2);
  int* labels        = (int*)(ws + O_LAB);
  float* tgts        = (float*)(ws + O_TGT);
  float* nll_v       = (float*)(ws + O_NLL);
  float* vc_v        = (float*)(ws + O_VC);
  float* sl1_v       = (float*)(ws + O_SL1);
  unsigned short* part = (unsigned short*)(ws + O_PART);
  unsigned char* feat8 = (unsigned char*)(ws + O_F8);

  // 1. prep: feature fp8 tile-image + weight image-transpose(x64) + head + matcher
  prep<<<NB_PREP, 256, 0, stream>>>(features, feat8, W1, W2, Wcls, Wbox,
                                    bcls, bbox, proposals, gt_boxes, gt_labels,
                                    W1t, W2t, Wh, bh, labels, tgts);

  // 2. GEMM1: KT=196, split-4 (nkt=49), pairs=33*4=132 -> grid 8*8*17=1088
  gemm_f8<<<1088, 256, 0, stream>>>(feat8, W1t, part, RT, REPD, FEATD/64, 49,
                                    8, 33, 132);
  reduce_fp8k<4><<<2048, 256, 0, stream>>>(part, b1, (unsigned int*)x1,
                                           (long)RT * REPD / 4, REPD / 4);

  // 3. GEMM2: KT=16, split-2 (nkt=8), pairs=66 -> grid 8*8*9=576
  gemm_f8<<<576, 256, 0, stream>>>(x1, W2t, part, RT, REPD, REPD/64, 8,
                                   8, 33, 66);
  reduce_fp8k<2><<<2048, 256, 0, stream>>>(part, b2, (unsigned int*)x2,
                                           (long)RT * REPD / 4, REPD / 4);

  // 4. GEMM3: KT=16, split-4 (nkt=4), Nc=512 (4 n-blocks), pairs=132 -> grid 544
  gemm_f8<<<544, 256, 0, stream>>>(x2, Wh, part, RT, NH, REPD/64, 4,
                                   4, 33, 132);

  // 5. losses (loss_row folds GEMM3's 4-slice reduce + bias + 1/WSC)
  loss_row<<<RT, 64, 0, stream>>>(part, bh, labels, tgts, nll_v, vc_v, sl1_v);
  reduce_final<<<1, 256, 0, stream>>>(nll_v, vc_v, sl1_v, out);
}

// Round 5
// 482.714 us; speedup vs baseline: 1.1728x; 1.0067x over previous
//
#include <hip/hip_runtime.h>
#include <cstdint>
#include <cstddef>

// ---- problem constants ----
#define BQ   8
#define NP   512
#define GQ   16
#define PP   528      // NP + GQ
#define RT   4224     // BQ * PP
#define CC   91
#define FEATD 12544
#define REPD 1024
#define NH   512      // padded head output cols (455 used: 91 cls + 364 box)
#define NHU  455
#define BETA (1.0f/9.0f)
#define WSC  64.0f    // fp8 weight pre-scale (exact pow2; undone in reduce/loss)

typedef float f32x4 __attribute__((ext_vector_type(4)));
typedef int   v8i  __attribute__((ext_vector_type(8)));
typedef float v16f __attribute__((ext_vector_type(16)));

__device__ __forceinline__ unsigned short f2bf(float f) {
  unsigned int x = __float_as_uint(f);
  unsigned int r = (x + 0x7fffu + ((x >> 16) & 1u)) >> 16;
  return (unsigned short)r;
}
__device__ __forceinline__ float bf2f(unsigned short u) {
  return __uint_as_float((unsigned int)u << 16);
}
__device__ __forceinline__ unsigned char f2fp8(float f) {
  return (unsigned char)(__builtin_amdgcn_cvt_pk_fp8_f32(f, 0.0f, 0, false) & 0xff);
}

// async global->LDS DMA, 16 B per lane; HW writes lane L to base + L*16.
__device__ __forceinline__ void ld_lds16(const void* g, void* l) {
  __builtin_amdgcn_global_load_lds(
      (const __attribute__((address_space(1))) void*)g,
      (__attribute__((address_space(3))) void*)l, 16, 0, 0);
}

// ---- tile-image layout --------------------------------------------------
// All GEMM operands are stored pre-tiled in global memory so that staging is
// PURE SEQUENTIAL global_load_lds (1024 contiguous bytes / instr = 8 full
// 128-B L2 lines) and LDS fragment reads are dense (zero bank conflicts).
// Image: 128-row x 64-kbyte tile = 8192 B, tiles ordered [rowblk][ktile].
// Within a tile: region w = (row>>5)&3 (2048 B), then [kc=(kb>>4)&3][r=row&31][16B].
// Fragment read (32 lanes, kc fixed): contiguous 512 B -> conflict-free.
__device__ __forceinline__ size_t img_off(int row, int kb, int KT) {
  return (size_t)((row >> 7) * KT + (kb >> 6)) * 8192
       + (size_t)((((row >> 5) & 3) << 11) + (((kb >> 4) & 3) << 9)
                  + ((row & 31) << 4) + (kb & 15));
}

// ---- workspace layout (bytes); total ~107 MB ----
constexpr size_t O_W1T = 0;
constexpr size_t SZ_W1T = (size_t)FEATD * REPD;             // W1^T fp8 image
constexpr size_t O_W2T = O_W1T + SZ_W1T;
constexpr size_t SZ_W2T = (size_t)REPD * REPD;              // W2^T fp8 image
constexpr size_t O_WH  = O_W2T + SZ_W2T;
constexpr size_t SZ_WH = (size_t)NH * REPD;                 // [Wcls|Wbox]^T fp8 image
constexpr size_t O_BH  = O_WH + SZ_WH;
constexpr size_t SZ_BH = (size_t)NH * 4;
constexpr size_t O_X1  = O_BH + SZ_BH;
constexpr size_t SZ_X1 = (size_t)RT * REPD;                 // x1 fp8 image
constexpr size_t O_X2  = O_X1 + SZ_X1;                      // x2 fp8 image
constexpr size_t O_LAB = O_X2 + SZ_X1;
constexpr size_t O_TGT = O_LAB + (size_t)RT * 4;
constexpr size_t O_NLL = O_TGT + (size_t)RT * 16;
constexpr size_t O_VC  = O_NLL + (size_t)RT * 4;
constexpr size_t O_SL1 = O_VC + (size_t)RT * 4;
constexpr size_t O_PART = ((O_SL1 + (size_t)RT * 4) + 255) & ~(size_t)255;
constexpr size_t SZ_PART = (size_t)4 * RT * REPD * 2;       // bf16 partials
constexpr size_t O_F8 = O_PART + SZ_PART;                   // fp8 feature image, 53 MB

// ---- prep ----
// CV: feature fp32 -> fp8 tile image DIRECTLY (no LDS): lane owns (row, 32-k
// span); 8 coalesced float4 loads -> 16 cvt_pk -> two dense 16-B slot stores.
// t32: weight 32x32 LDS transpose, then 16-B packed slot stores (t<64).
__device__ __forceinline__ void t32(const float* __restrict__ in, unsigned char* __restrict__ out,
                                    int K, int N, int row_off, int KT,
                                    int bx, int by, int t, float (*tile)[33]) {
  int tx = t & 31, ty = t >> 5;
  int n0 = bx * 32, k0 = by * 32;
#pragma unroll
  for (int i = 0; i < 4; ++i) {
    int k = k0 + ty + i * 8, n = n0 + tx;
    if (k < K && n < N) tile[ty + i * 8][tx] = in[(size_t)k * N + n];
  }
  __syncthreads();
  if (t < 64) {
    int rn = t & 31, kc = t >> 5;            // slot = (row n0+rn, k chunk k0+kc*16)
    int n = n0 + rn;
    if (n < N) {
      unsigned int pk[4];
#pragma unroll
      for (int q = 0; q < 4; ++q) {
        float f0 = tile[kc * 16 + q * 4 + 0][rn] * WSC;
        float f1 = tile[kc * 16 + q * 4 + 1][rn] * WSC;
        float f2 = tile[kc * 16 + q * 4 + 2][rn] * WSC;
        float f3 = tile[kc * 16 + q * 4 + 3][rn] * WSC;
        unsigned int r = (unsigned int)__builtin_amdgcn_cvt_pk_fp8_f32(f0, f1, 0, false);
        pk[q] = (unsigned int)__builtin_amdgcn_cvt_pk_fp8_f32(f2, f3, (int)r, true);
      }
      int4 v; v.x = (int)pk[0]; v.y = (int)pk[1]; v.z = (int)pk[2]; v.w = (int)pk[3];
      *(int4*)&out[img_off(n + row_off, k0 + kc * 16, KT)] = v;
    }
  }
}

#define NB_CV ((RT/128)*(FEATD/64))      // 33*196 = 6468 tile blocks
#define NB_W1 ((REPD/32)*(FEATD/32))     // 12544
#define NB_W2 ((REPD/32)*(REPD/32))      // 1024
#define NB_WC (3*(REPD/32))              // 96
#define NB_WB (12*(REPD/32))             // 384
#define NB_HI 230
#define NB_MT 17
#define NB_PREP (NB_CV+NB_W1+NB_W2+NB_WC+NB_WB+NB_HI+NB_MT)

__global__ void prep(const float* __restrict__ feat, unsigned char* __restrict__ feat8,
                     const float* __restrict__ W1, const float* __restrict__ W2,
                     const float* __restrict__ Wcls, const float* __restrict__ Wbox,
                     const float* __restrict__ bcls, const float* __restrict__ bbox,
                     const float* __restrict__ proposals, const float* __restrict__ gt_boxes,
                     const int* __restrict__ gt_labels,
                     unsigned char* __restrict__ W1t, unsigned char* __restrict__ W2t,
                     unsigned char* __restrict__ Wh, float* __restrict__ bh,
                     int* __restrict__ labels, float* __restrict__ tgts) {
  __shared__ float tile[32][33];
  int b = blockIdx.x, t = threadIdx.x;
  if (b < NB_CV) {
    // 128-row x 64-kbyte tile, LDS-free: lane (w,L) owns row w*32+(L&31),
    // k-span (L>>5)*32 floats. Reads: 8x float4 (one 128-B line per lane).
    // Writes: two 16-B slots; per half-wave 32x16 B = 512 B dense.
    int yb = b / (FEATD / 64), kt = b % (FEATD / 64);
    const int w = t >> 6, L = t & 63;
    const int rl = L & 31, h = L >> 5;
    const float* src = feat + (size_t)(yb * 128 + w * 32 + rl) * FEATD + kt * 64 + h * 32;
    unsigned char* dst = feat8 + (size_t)b * 8192 + w * 2048 + rl * 16;
    unsigned int pk[8];
#pragma unroll
    for (int c = 0; c < 8; ++c) {
      float4 f = ((const float4*)src)[c];
      unsigned int r = (unsigned int)__builtin_amdgcn_cvt_pk_fp8_f32(f.x, f.y, 0, false);
      pk[c] = (unsigned int)__builtin_amdgcn_cvt_pk_fp8_f32(f.z, f.w, (int)r, true);
    }
    int4 v0; v0.x = (int)pk[0]; v0.y = (int)pk[1]; v0.z = (int)pk[2]; v0.w = (int)pk[3];
    int4 v1; v1.x = (int)pk[4]; v1.y = (int)pk[5]; v1.z = (int)pk[6]; v1.w = (int)pk[7];
    *(int4*)(dst + (2 * h) * 512) = v0;       // kc = 2h
    *(int4*)(dst + (2 * h + 1) * 512) = v1;   // kc = 2h+1
    return;
  }
  b -= NB_CV;
  if (b < NB_W1) { t32(W1, W1t, FEATD, REPD, 0, FEATD/64, b % (REPD/32), b / (REPD/32), t, tile); return; }
  b -= NB_W1;
  if (b < NB_W2) { t32(W2, W2t, REPD, REPD, 0, REPD/64, b % 32, b / 32, t, tile); return; }
  b -= NB_W2;
  if (b < NB_WC) { t32(Wcls, Wh, REPD, CC, 0, REPD/64, b % 3, b / 3, t, tile); return; }
  b -= NB_WC;
  if (b < NB_WB) { t32(Wbox, Wh, REPD, 4 * CC, CC, REPD/64, b % 12, b / 12, t, tile); return; }
  b -= NB_WB;
  if (b < NB_HI) {
    int idx = b * 256 + t;
    const int npad = (NH - NHU) * REPD;   // 58368 fp8 zeros (rows 455..511)
    if (idx < npad) {
      int row = NHU + (idx >> 10), k = idx & 1023;
      Wh[img_off(row, k, REPD/64)] = 0;
    } else {
      int i2 = idx - npad;
      if (i2 < NH) bh[i2] = (i2 < CC) ? bcls[i2] : (i2 < NHU ? bbox[i2 - CC] : 0.0f);
    }
    return;
  }
  b -= NB_HI;
  // ---- matcher + encode (exact fp32) ----
  int r = b * 256 + t;
  if (r >= RT) return;
  int bi_ = r / PP, p = r % PP;
  float x0, y0, x1, y1;
  if (p < NP) {
    const float* qq = proposals + ((size_t)bi_ * NP + p) * 4;
    x0 = qq[0]; y0 = qq[1]; x1 = qq[2]; y1 = qq[3];
  } else {
    const float* qq = gt_boxes + ((size_t)bi_ * GQ + (p - NP)) * 4;
    x0 = qq[0]; y0 = qq[1]; x1 = qq[2]; y1 = qq[3];
  }
  float ap = (x1 - x0) * (y1 - y0);
  float best = -1.0f; int bg = 0;
#pragma unroll
  for (int g = 0; g < GQ; ++g) {
    const float* gb = gt_boxes + ((size_t)bi_ * GQ + g) * 4;
    float gx0 = gb[0], gy0 = gb[1], gx1 = gb[2], gy1 = gb[3];
    float ag = (gx1 - gx0) * (gy1 - gy0);
    float iw = fmaxf(fminf(gx1, x1) - fmaxf(gx0, x0), 0.0f);
    float ih = fmaxf(fminf(gy1, y1) - fmaxf(gy0, y0), 0.0f);
    float inter = iw * ih;
    float iou = inter / (ag + ap - inter);
    if (iou > best) { best = iou; bg = g; }   // strict > keeps first max (jnp.argmax)
  }
  int lab = gt_labels[bi_ * GQ + bg];
  if (best < 0.5f) lab = 0;    // FG==BG==0.5 -> ignore band empty
  labels[r] = lab;
  const float* gb = gt_boxes + ((size_t)bi_ * GQ + bg) * 4;
  float ew = x1 - x0, eh = y1 - y0;
  float ex = x0 + 0.5f * ew, ey = y0 + 0.5f * eh;
  float gw = gb[2] - gb[0], gh = gb[3] - gb[1];
  float gx = gb[0] + 0.5f * gw, gy = gb[1] + 0.5f * gh;
  tgts[r * 4 + 0] = 10.0f * (gx - ex) / ew;
  tgts[r * 4 + 1] = 10.0f * (gy - ey) / eh;
  tgts[r * 4 + 2] = 5.0f * logf(gw / ew);
  tgts[r * 4 + 3] = 5.0f * logf(gh / eh);
}

// ---- MX-scaled fp8 GEMM on tile images: 128x128, BK=64, dbuf, vmcnt(4) ----
// Staging = linear global_load_lds of the pre-tiled image (1024 contiguous
// bytes/instr, sequential across iters). Fragment ds_read_b128: two dense
// 512-B spans -> zero bank conflicts. XCD pair-mapping (no stagger): 8
// n-blocks sharing one A-slice run lockstep on ONE XCD -> A L2-dedup'd.
__global__ __launch_bounds__(256, 4)
void gemm_f8(const unsigned char* __restrict__ Aimg, const unsigned char* __restrict__ Bimg,
             unsigned short* __restrict__ P, int M, int Nc, int KT, int nkt,
             int n_nblk, int n_my, int npairs) {
  __shared__ unsigned char As[2 * 8192];
  __shared__ unsigned char Bs[2 * 8192];

  const int g = blockIdx.x;
  const int xcd = g & 7;
  const int kix = g >> 3;
  const int n  = kix % n_nblk;
  const int pi = kix / n_nblk;
  const int p  = pi * 8 + xcd;
  if (p >= npairs) return;                 // uniform dummy exit, before any barrier
  const int y  = p % n_my;
  const int kz = p / n_my;
  const int m0 = y * 128, n0 = n * 128;

  const int tid = threadIdx.x;
  const int w = tid >> 6, L = tid & 63;
  const int l31 = L & 31, h = L >> 5;
  const int wr = (w >> 1) * 64, wc = (w & 1) * 64;

  const int kt0 = kz * nkt;
  const unsigned char* gA = Aimg + ((size_t)y * KT + kt0) * 8192 + w * 2048 + L * 16;
  const unsigned char* gB = Bimg + ((size_t)n * KT + kt0) * 8192 + w * 2048 + L * 16;
  const int lw = w * 2048;                 // wave w stages region w

#define STAGE(it, bufo) do {                                    \
    const size_t _go = (size_t)(it) * 8192;                     \
    ld_lds16(gA + _go,        &As[(bufo) + lw]);                \
    ld_lds16(gA + _go + 1024, &As[(bufo) + lw + 1024]);         \
    ld_lds16(gB + _go,        &Bs[(bufo) + lw]);                \
    ld_lds16(gB + _go + 1024, &Bs[(bufo) + lw + 1024]);         \
  } while (0)

  // fragment base: A rows wr+i*32+l31 -> region (wr>>5)+i; chunk 2h at h*1024,
  // chunk 2h+1 at +512. 32 lanes same kc = contiguous 512 B (conflict-free).
  int aoff[2], boff[2];
#pragma unroll
  for (int i = 0; i < 2; ++i) {
    aoff[i] = (((w >> 1) * 2 + i) << 11) + (h << 10) + (l31 << 4);
    boff[i] = (((w & 1) * 2 + i) << 11) + (h << 10) + (l31 << 4);
  }

  STAGE(0, 0);                              // prologue: tile 0 -> buffer 0

  v16f acc[2][2] = {};
  int cur = 0;
  for (int it = 0; it < nkt; ++it) {
    const int cb = cur << 13;
    if (it + 1 < nkt) {
      STAGE(it + 1, cb ^ 8192);             // next tile's 4 DMA stay in flight
      asm volatile("s_waitcnt vmcnt(4)" ::: "memory");
    } else {
      asm volatile("s_waitcnt vmcnt(0)" ::: "memory");
    }
    __builtin_amdgcn_sched_barrier(0);
    __builtin_amdgcn_s_barrier();           // tile staged for all waves

    v8i a[2], b[2];
#pragma unroll
    for (int i = 0; i < 2; ++i) {
      int4 alo = *(const int4*)&As[cb + aoff[i]];
      int4 ahi = *(const int4*)&As[cb + aoff[i] + 512];
      a[i] = (v8i){alo.x, alo.y, alo.z, alo.w, ahi.x, ahi.y, ahi.z, ahi.w};
      int4 blo = *(const int4*)&Bs[cb + boff[i]];
      int4 bhi = *(const int4*)&Bs[cb + boff[i] + 512];
      b[i] = (v8i){blo.x, blo.y, blo.z, blo.w, bhi.x, bhi.y, bhi.z, bhi.w};
    }
#pragma unroll
    for (int i = 0; i < 2; ++i)
#pragma unroll
      for (int j = 0; j < 2; ++j)
        acc[i][j] = __builtin_amdgcn_mfma_scale_f32_32x32x64_f8f6f4(
            a[i], b[j], acc[i][j], 0, 0, 0, 127, 0, 127);  // fp8/fp8, scales=2^0

    asm volatile("s_waitcnt lgkmcnt(0)" ::: "memory");
    __builtin_amdgcn_sched_barrier(0);
    __builtin_amdgcn_s_barrier();           // all waves done -> buffer reusable
    cur ^= 1;
  }
#undef STAGE

  // epilogue: 32x32 C/D layout col=l&31, row=(reg&3)+8*(reg>>2)+4*(l>>5) -> bf16
  unsigned short* Pz = P + (size_t)kz * M * Nc;
#pragma unroll
  for (int i = 0; i < 2; ++i) {
#pragma unroll
    for (int j = 0; j < 2; ++j) {
      int colb = n0 + wc + j * 32 + l31;
#pragma unroll
      for (int r = 0; r < 16; ++r) {
        int row = m0 + wr + i * 32 + (r & 3) + 8 * (r >> 2) + 4 * h;
        Pz[(size_t)row * Nc + colb] = f2bf(acc[i][j][r]);
      }
    }
  }
}

// ---- split-K reduce (bf16 partials) + 1/WSC + bias + ReLU -> fp8 image ----
template <int S>
__global__ void reduce_fp8k(const unsigned short* __restrict__ P, const float* __restrict__ bias,
                            unsigned int* __restrict__ outp, long MN4, int nc4) {
  long i = (long)blockIdx.x * blockDim.x + threadIdx.x;
  long stride = (long)gridDim.x * blockDim.x;
  const ushort4* P4 = (const ushort4*)P;
  const float4* B4 = (const float4*)bias;
  for (; i < MN4; i += stride) {
    float vx = 0, vy = 0, vz = 0, vw = 0;
#pragma unroll
    for (int s = 0; s < S; ++s) {
      ushort4 u = P4[s * MN4 + i];
      vx += bf2f(u.x); vy += bf2f(u.y); vz += bf2f(u.z); vw += bf2f(u.w);
    }
    float4 b = B4[i & (nc4 - 1)];
    vx = fmaxf(vx * (1.0f / WSC) + b.x, 0.0f);
    vy = fmaxf(vy * (1.0f / WSC) + b.y, 0.0f);
    vz = fmaxf(vz * (1.0f / WSC) + b.z, 0.0f);
    vw = fmaxf(vw * (1.0f / WSC) + b.w, 0.0f);
    unsigned int r = (unsigned int)__builtin_amdgcn_cvt_pk_fp8_f32(vx, vy, 0, false);
    r = (unsigned int)__builtin_amdgcn_cvt_pk_fp8_f32(vz, vw, (int)r, true);
    // store into tile-image position (row rr, kbyte kb), KT = REPD/64 = 16
    int rr = (int)(i >> 8);
    int kb = ((int)i & 255) * 4;
    outp[img_off(rr, kb, REPD / 64) >> 2] = r;
  }
}

// ---- per-row loss, reading GEMM3's 4 bf16 split-K slices + bias directly ----
__global__ void loss_row(const unsigned short* __restrict__ P, const float* __restrict__ bh,
                         const int* __restrict__ labels, const float* __restrict__ tgts,
                         float* __restrict__ nll_v, float* __restrict__ vc_v,
                         float* __restrict__ sl1_v) {
  int r = blockIdx.x;
  int l = threadIdx.x;
  const size_t SL = (size_t)RT * NH;
  const unsigned short* p0 = P + (size_t)r * NH;
#define COLV(c) ((bf2f(p0[(c)]) + bf2f(p0[SL + (c)]) + bf2f(p0[2 * SL + (c)]) + \
                  bf2f(p0[3 * SL + (c)])) * (1.0f / WSC) + bh[(c)])
  float v1 = COLV(l);
  float v2 = (l < CC - 64) ? COLV(64 + l) : -3.4e38f;
  float m = fmaxf(v1, v2);
#pragma unroll
  for (int o = 32; o; o >>= 1) m = fmaxf(m, __shfl_xor(m, o));
  float e = __expf(v1 - m) + ((l < CC - 64) ? __expf(v2 - m) : 0.0f);
#pragma unroll
  for (int o = 32; o; o >>= 1) e += __shfl_xor(e, o);
  if (l == 0) {
    float lse = m + __logf(e);
    int lab = labels[r];
    int sl = lab < 0 ? 0 : (lab > CC - 1 ? CC - 1 : lab);
    float valid = (lab >= 0) ? 1.0f : 0.0f;
    nll_v[r] = (lse - COLV(sl)) * valid;
    vc_v[r] = valid;
    float s = 0.0f;
#pragma unroll
    for (int d = 0; d < 4; ++d) {
      float pd = COLV(CC + sl * 4 + d);
      float ad = fabsf(pd - tgts[r * 4 + d]);
      s += (ad < BETA) ? 0.5f * ad * ad / BETA : ad - 0.5f * BETA;
    }
    sl1_v[r] = (lab > 0) ? s : 0.0f;
  }
#undef COLV
}

// ---- deterministic final reduce ----
__global__ void reduce_final(const float* __restrict__ nll_v, const float* __restrict__ vc_v,
                             const float* __restrict__ sl1_v, float* __restrict__ out) {
  __shared__ float s1[256], s2[256], s3[256];
  int t = threadIdx.x;
  float a = 0, b = 0, c = 0;
  for (int i = t; i < RT; i += 256) { a += nll_v[i]; b += vc_v[i]; c += sl1_v[i]; }
  s1[t] = a; s2[t] = b; s3[t] = c;
  __syncthreads();
  for (int o = 128; o; o >>= 1) {
    if (t < o) { s1[t] += s1[t + o]; s2[t] += s2[t + o]; s3[t] += s3[t + o]; }
    __syncthreads();
  }
  if (t == 0) {
    out[0] = s1[0] / fmaxf(s2[0], 1.0f);
    out[1] = s3[0] / (float)RT;
  }
}

extern "C" void kernel_launch(void* const* d_in, const int* in_sizes, int n_in,
                              void* d_out, int out_size, void* d_ws, size_t ws_size,
                              hipStream_t stream) {
  const float* proposals = (const float*)d_in[0];
  const float* gt_boxes  = (const float*)d_in[1];
  const float* features  = (const float*)d_in[2];
  const float* W1   = (const float*)d_in[3];
  const float* b1   = (const float*)d_in[4];
  const float* W2   = (const float*)d_in[5];
  const float* b2   = (const float*)d_in[6];
  const float* Wcls = (const float*)d_in[7];
  const float* bcls = (const float*)d_in[8];
  const float* Wbox = (const float*)d_in[9];
  const float* bbox = (const float*)d_in[10];
  const int* gt_labels = (const int*)d_in[11];
  float* out = (float*)d_out;

  char* ws = (char*)d_ws;
  unsigned char* W1t = (unsigned char*)(ws + O_W1T);
  unsigned char* W2t = (unsigned char*)(ws + O_W2T);
  unsigned char* Wh  = (unsigned char*)(ws + O_WH);
  float* bh          = (float*)(ws + O_BH);
  unsigned char* x1  = (unsigned char*)(ws + O_X1);
  unsigned char* x2  = (unsigned char*)(ws + O_X2);
  int* labels        = (int*)(ws + O_LAB);
  float* tgts        = (float*)(ws + O_TGT);
  float* nll_v       = (float*)(ws + O_NLL);
  float* vc_v        = (float*)(ws + O_VC);
  float* sl1_v       = (float*)(ws + O_SL1);
  unsigned short* part = (unsigned short*)(ws + O_PART);
  unsigned char* feat8 = (unsigned char*)(ws + O_F8);

  // 1. prep: feature fp8 tile-image + weight image-transpose(x64) + head + matcher
  prep<<<NB_PREP, 256, 0, stream>>>(features, feat8, W1, W2, Wcls, Wbox,
                                    bcls, bbox, proposals, gt_boxes, gt_labels,
                                    W1t, W2t, Wh, bh, labels, tgts);

  // 2. GEMM1: KT=196, split-4 (nkt=49), pairs=33*4=132 -> grid 8*8*17=1088
  gemm_f8<<<1088, 256, 0, stream>>>(feat8, W1t, part, RT, REPD, FEATD/64, 49,
                                    8, 33, 132);
  reduce_fp8k<4><<<2048, 256, 0, stream>>>(part, b1, (unsigned int*)x1,
                                           (long)RT * REPD / 4, REPD / 4);

  // 3. GEMM2: KT=16, split-2 (nkt=8), pairs=66 -> grid 8*8*9=576
  gemm_f8<<<576, 256, 0, stream>>>(x1, W2t, part, RT, REPD, REPD/64, 8,
                                   8, 33, 66);
  reduce_fp8k<2><<<2048, 256, 0, stream>>>(part, b2, (unsigned int*)x2,
                                           (long)RT * REPD / 4, REPD / 4);

  // 4. GEMM3: KT=16, split-4 (nkt=4), Nc=512 (4 n-blocks), pairs=132 -> grid 544
  gemm_f8<<<544, 256, 0, stream>>>(x2, Wh, part, RT, NH, REPD/64, 4,
                                   4, 33, 132);

  // 5. losses (loss_row folds GEMM3's 4-slice reduce + bias + 1/WSC)
  loss_row<<<RT, 64, 0, stream>>>(part, bh, labels, tgts, nll_v, vc_v, sl1_v);
  reduce_final<<<1, 256, 0, stream>>>(nll_v, vc_v, sl1_v, out);
}

// Round 6
// 482.134 us; speedup vs baseline: 1.1742x; 1.0012x over previous
//
#include <hip/hip_runtime.h>
#include <cstdint>
#include <cstddef>

// ---- problem constants ----
#define BQ   8
#define NP   512
#define GQ   16
#define PP   528      // NP + GQ
#define RT   4224     // BQ * PP
#define CC   91
#define FEATD 12544
#define REPD 1024
#define NH   512      // padded head output cols (455 used: 91 cls + 364 box)
#define NHU  455
#define BETA (1.0f/9.0f)
#define WSC  64.0f    // fp8 weight pre-scale (exact pow2; undone in reduce/loss)

typedef float f32x4 __attribute__((ext_vector_type(4)));
typedef int   v8i  __attribute__((ext_vector_type(8)));
typedef float v16f __attribute__((ext_vector_type(16)));

__device__ __forceinline__ unsigned short f2bf(float f) {
  unsigned int x = __float_as_uint(f);
  unsigned int r = (x + 0x7fffu + ((x >> 16) & 1u)) >> 16;
  return (unsigned short)r;
}
__device__ __forceinline__ float bf2f(unsigned short u) {
  return __uint_as_float((unsigned int)u << 16);
}

// async global->LDS DMA, 16 B per lane; HW writes lane L to base + L*16.
__device__ __forceinline__ void ld_lds16(const void* g, void* l) {
  __builtin_amdgcn_global_load_lds(
      (const __attribute__((address_space(1))) void*)g,
      (__attribute__((address_space(3))) void*)l, 16, 0, 0);
}

// ---- tile-image layout --------------------------------------------------
// Image: 128-row x 64-kbyte tile = 8192 B, tiles ordered [rowblk][ktile].
// Within a tile: region (row>>5)&3 (2048 B), then [kc=(kb>>4)&3][r=row&31][16B].
__device__ __forceinline__ size_t img_off(int row, int kb, int KT) {
  return (size_t)((row >> 7) * KT + (kb >> 6)) * 8192
       + (size_t)((((row >> 5) & 3) << 11) + (((kb >> 4) & 3) << 9)
                  + ((row & 31) << 4) + (kb & 15));
}

// ---- workspace layout (bytes); total ~107 MB ----
constexpr size_t O_W1T = 0;
constexpr size_t SZ_W1T = (size_t)FEATD * REPD;             // W1^T fp8 image
constexpr size_t O_W2T = O_W1T + SZ_W1T;
constexpr size_t SZ_W2T = (size_t)REPD * REPD;              // W2^T fp8 image
constexpr size_t O_WH  = O_W2T + SZ_W2T;
constexpr size_t SZ_WH = (size_t)NH * REPD;                 // [Wcls|Wbox]^T fp8 image
constexpr size_t O_BH  = O_WH + SZ_WH;
constexpr size_t SZ_BH = (size_t)NH * 4;
constexpr size_t O_X1  = O_BH + SZ_BH;
constexpr size_t SZ_X1 = (size_t)RT * REPD;                 // x1 fp8 image
constexpr size_t O_X2  = O_X1 + SZ_X1;                      // x2 fp8 image
constexpr size_t O_LAB = O_X2 + SZ_X1;
constexpr size_t O_TGT = O_LAB + (size_t)RT * 4;
constexpr size_t O_NLL = O_TGT + (size_t)RT * 16;
constexpr size_t O_VC  = O_NLL + (size_t)RT * 4;
constexpr size_t O_SL1 = O_VC + (size_t)RT * 4;
constexpr size_t O_PART = ((O_SL1 + (size_t)RT * 4) + 255) & ~(size_t)255;
constexpr size_t SZ_PART = (size_t)4 * RT * REPD * 2;       // bf16 partials
constexpr size_t O_F8 = O_PART + SZ_PART;                   // fp8 feature image, 53 MB

// ===== prep_cv: feature fp32 -> fp8 tile image (LDS-free, R5-proven) =====
#define NB_CV ((RT/128)*(FEATD/64))      // 33*196 = 6468 tile blocks
__global__ void prep_cv(const float* __restrict__ feat, unsigned char* __restrict__ feat8) {
  int b = blockIdx.x, t = threadIdx.x;
  int yb = b / (FEATD / 64), kt = b % (FEATD / 64);
  const int w = t >> 6, L = t & 63;
  const int rl = L & 31, h = L >> 5;
  const float* src = feat + (size_t)(yb * 128 + w * 32 + rl) * FEATD + kt * 64 + h * 32;
  unsigned char* dst = feat8 + (size_t)b * 8192 + w * 2048 + rl * 16;
  unsigned int pk[8];
#pragma unroll
  for (int c = 0; c < 8; ++c) {
    float4 f = ((const float4*)src)[c];
    unsigned int r = (unsigned int)__builtin_amdgcn_cvt_pk_fp8_f32(f.x, f.y, 0, false);
    pk[c] = (unsigned int)__builtin_amdgcn_cvt_pk_fp8_f32(f.z, f.w, (int)r, true);
  }
  int4 v0; v0.x = (int)pk[0]; v0.y = (int)pk[1]; v0.z = (int)pk[2]; v0.w = (int)pk[3];
  int4 v1; v1.x = (int)pk[4]; v1.y = (int)pk[5]; v1.z = (int)pk[6]; v1.w = (int)pk[7];
  *(int4*)(dst + (2 * h) * 512) = v0;       // kc = 2h
  *(int4*)(dst + (2 * h + 1) * 512) = v1;   // kc = 2h+1
}

// ===== prep_w: weight transpose-convert(x64) -> tile image ==============
// Block = 32 n-rows x 128 k: float4 global loads (8 lanes/128-B segment),
// float4 LDS stores (36-float row stride, conflict-free), then ALL 256
// threads pack one 16-B image slot (rn=t&31, kc=t>>5).
__device__ __forceinline__ void tr128(const float* __restrict__ in, unsigned char* __restrict__ out,
                                      int K, int N, int row_off, int KT,
                                      int bx, int by, int t, float (*tile)[36]) {
  const int n0 = bx * 32, k0 = by * 128;
  const int n4 = t & 7, kr = t >> 3;       // kr 0..31
  if (n0 + 32 <= N) {
#pragma unroll
    for (int i = 0; i < 4; ++i) {
      int k = k0 + kr + i * 32;
      float4 f = *(const float4*)&in[(size_t)k * N + n0 + n4 * 4];
      *(float4*)&tile[kr + i * 32][n4 * 4] = f;
    }
  } else {
#pragma unroll
    for (int i = 0; i < 4; ++i) {
      int k = k0 + kr + i * 32;
#pragma unroll
      for (int j = 0; j < 4; ++j) {
        int n = n0 + n4 * 4 + j;
        tile[kr + i * 32][n4 * 4 + j] = (n < N) ? in[(size_t)k * N + n] : 0.0f;
      }
    }
  }
  __syncthreads();
  const int rn = t & 31, kc = t >> 5;      // kc 0..7 (16 k each)
  const int n = n0 + rn;
  if (n < N) {
    unsigned int pk[4];
#pragma unroll
    for (int q = 0; q < 4; ++q) {
      float f0 = tile[kc * 16 + q * 4 + 0][rn] * WSC;
      float f1 = tile[kc * 16 + q * 4 + 1][rn] * WSC;
      float f2 = tile[kc * 16 + q * 4 + 2][rn] * WSC;
      float f3 = tile[kc * 16 + q * 4 + 3][rn] * WSC;
      unsigned int r = (unsigned int)__builtin_amdgcn_cvt_pk_fp8_f32(f0, f1, 0, false);
      pk[q] = (unsigned int)__builtin_amdgcn_cvt_pk_fp8_f32(f2, f3, (int)r, true);
    }
    int4 v; v.x = (int)pk[0]; v.y = (int)pk[1]; v.z = (int)pk[2]; v.w = (int)pk[3];
    *(int4*)&out[img_off(n + row_off, k0 + kc * 16, KT)] = v;
  }
}

#define NBW1 ((REPD/32)*(FEATD/128))     // 32*98 = 3136
#define NBW2 ((REPD/32)*(REPD/128))      // 32*8  = 256
#define NBWC (3*(REPD/128))              // 24
#define NBWB (12*(REPD/128))             // 96
#define NB_PW (NBW1+NBW2+NBWC+NBWB)      // 3512

__global__ void prep_w(const float* __restrict__ W1, const float* __restrict__ W2,
                       const float* __restrict__ Wcls, const float* __restrict__ Wbox,
                       unsigned char* __restrict__ W1t, unsigned char* __restrict__ W2t,
                       unsigned char* __restrict__ Wh) {
  __shared__ float tile[128][36];
  int b = blockIdx.x, t = threadIdx.x;
  if (b < NBW1) { tr128(W1, W1t, FEATD, REPD, 0, FEATD/64, b % 32, b / 32, t, tile); return; }
  b -= NBW1;
  if (b < NBW2) { tr128(W2, W2t, REPD, REPD, 0, REPD/64, b % 32, b / 32, t, tile); return; }
  b -= NBW2;
  if (b < NBWC) { tr128(Wcls, Wh, REPD, CC, 0, REPD/64, b % 3, b / 3, t, tile); return; }
  b -= NBWC;
  tr128(Wbox, Wh, REPD, 4 * CC, CC, REPD/64, b % 12, b / 12, t, tile);
}

// ===== prep_misc: head pad/bias init + matcher/encode ===================
#define NB_HI 230
#define NB_MT 17
#define NB_MISC (NB_HI+NB_MT)
__global__ void prep_misc(const float* __restrict__ bcls, const float* __restrict__ bbox,
                          const float* __restrict__ proposals, const float* __restrict__ gt_boxes,
                          const int* __restrict__ gt_labels,
                          unsigned char* __restrict__ Wh, float* __restrict__ bh,
                          int* __restrict__ labels, float* __restrict__ tgts) {
  int b = blockIdx.x, t = threadIdx.x;
  if (b < NB_HI) {
    int idx = b * 256 + t;
    const int npad = (NH - NHU) * REPD;   // 58368 fp8 zeros (rows 455..511)
    if (idx < npad) {
      int row = NHU + (idx >> 10), k = idx & 1023;
      Wh[img_off(row, k, REPD/64)] = 0;
    } else {
      int i2 = idx - npad;
      if (i2 < NH) bh[i2] = (i2 < CC) ? bcls[i2] : (i2 < NHU ? bbox[i2 - CC] : 0.0f);
    }
    return;
  }
  b -= NB_HI;
  // ---- matcher + encode (exact fp32) ----
  int r = b * 256 + t;
  if (r >= RT) return;
  int bi_ = r / PP, p = r % PP;
  float x0, y0, x1, y1;
  if (p < NP) {
    const float* qq = proposals + ((size_t)bi_ * NP + p) * 4;
    x0 = qq[0]; y0 = qq[1]; x1 = qq[2]; y1 = qq[3];
  } else {
    const float* qq = gt_boxes + ((size_t)bi_ * GQ + (p - NP)) * 4;
    x0 = qq[0]; y0 = qq[1]; x1 = qq[2]; y1 = qq[3];
  }
  float ap = (x1 - x0) * (y1 - y0);
  float best = -1.0f; int bg = 0;
#pragma unroll
  for (int g = 0; g < GQ; ++g) {
    const float* gb = gt_boxes + ((size_t)bi_ * GQ + g) * 4;
    float gx0 = gb[0], gy0 = gb[1], gx1 = gb[2], gy1 = gb[3];
    float ag = (gx1 - gx0) * (gy1 - gy0);
    float iw = fmaxf(fminf(gx1, x1) - fmaxf(gx0, x0), 0.0f);
    float ih = fmaxf(fminf(gy1, y1) - fmaxf(gy0, y0), 0.0f);
    float inter = iw * ih;
    float iou = inter / (ag + ap - inter);
    if (iou > best) { best = iou; bg = g; }   // strict > keeps first max (jnp.argmax)
  }
  int lab = gt_labels[bi_ * GQ + bg];
  if (best < 0.5f) lab = 0;    // FG==BG==0.5 -> ignore band empty
  labels[r] = lab;
  const float* gb = gt_boxes + ((size_t)bi_ * GQ + bg) * 4;
  float ew = x1 - x0, eh = y1 - y0;
  float ex = x0 + 0.5f * ew, ey = y0 + 0.5f * eh;
  float gw = gb[2] - gb[0], gh = gb[3] - gb[1];
  float gx = gb[0] + 0.5f * gw, gy = gb[1] + 0.5f * gh;
  tgts[r * 4 + 0] = 10.0f * (gx - ex) / ew;
  tgts[r * 4 + 1] = 10.0f * (gy - ey) / eh;
  tgts[r * 4 + 2] = 5.0f * logf(gw / ew);
  tgts[r * 4 + 3] = 5.0f * logf(gh / eh);
}

// ---- MX-scaled fp8 GEMM on tile images: 128x128, BK=64, dbuf, vmcnt(4) ----
// Staging = linear global_load_lds of the pre-tiled image (1024 contiguous
// bytes/instr). Fragment ds_read_b128: dense 512-B spans -> zero conflicts.
// XCD pair-mapping: 8 n-blocks sharing one A-slice run lockstep on ONE XCD.
__global__ __launch_bounds__(256, 4)
void gemm_f8(const unsigned char* __restrict__ Aimg, const unsigned char* __restrict__ Bimg,
             unsigned short* __restrict__ P, int M, int Nc, int KT, int nkt,
             int n_nblk, int n_my, int npairs) {
  __shared__ unsigned char As[2 * 8192];
  __shared__ unsigned char Bs[2 * 8192];

  const int g = blockIdx.x;
  const int xcd = g & 7;
  const int kix = g >> 3;
  const int n  = kix % n_nblk;
  const int pi = kix / n_nblk;
  const int p  = pi * 8 + xcd;
  if (p >= npairs) return;                 // uniform dummy exit, before any barrier
  const int y  = p % n_my;
  const int kz = p / n_my;
  const int m0 = y * 128, n0 = n * 128;

  const int tid = threadIdx.x;
  const int w = tid >> 6, L = tid & 63;
  const int l31 = L & 31, h = L >> 5;
  const int wr = (w >> 1) * 64, wc = (w & 1) * 64;

  const int kt0 = kz * nkt;
  const unsigned char* gA = Aimg + ((size_t)y * KT + kt0) * 8192 + w * 2048 + L * 16;
  const unsigned char* gB = Bimg + ((size_t)n * KT + kt0) * 8192 + w * 2048 + L * 16;
  const int lw = w * 2048;                 // wave w stages region w

#define STAGE(it, bufo) do {                                    \
    const size_t _go = (size_t)(it) * 8192;                     \
    ld_lds16(gA + _go,        &As[(bufo) + lw]);                \
    ld_lds16(gA + _go + 1024, &As[(bufo) + lw + 1024]);         \
    ld_lds16(gB + _go,        &Bs[(bufo) + lw]);                \
    ld_lds16(gB + _go + 1024, &Bs[(bufo) + lw + 1024]);         \
  } while (0)

  int aoff[2], boff[2];
#pragma unroll
  for (int i = 0; i < 2; ++i) {
    aoff[i] = (((w >> 1) * 2 + i) << 11) + (h << 10) + (l31 << 4);
    boff[i] = (((w & 1) * 2 + i) << 11) + (h << 10) + (l31 << 4);
  }

  STAGE(0, 0);                              // prologue: tile 0 -> buffer 0

  v16f acc[2][2] = {};
  int cur = 0;
  for (int it = 0; it < nkt; ++it) {
    const int cb = cur << 13;
    if (it + 1 < nkt) {
      STAGE(it + 1, cb ^ 8192);             // next tile's 4 DMA stay in flight
      asm volatile("s_waitcnt vmcnt(4)" ::: "memory");
    } else {
      asm volatile("s_waitcnt vmcnt(0)" ::: "memory");
    }
    __builtin_amdgcn_sched_barrier(0);
    __builtin_amdgcn_s_barrier();           // tile staged for all waves

    v8i a[2], b[2];
#pragma unroll
    for (int i = 0; i < 2; ++i) {
      int4 alo = *(const int4*)&As[cb + aoff[i]];
      int4 ahi = *(const int4*)&As[cb + aoff[i] + 512];
      a[i] = (v8i){alo.x, alo.y, alo.z, alo.w, ahi.x, ahi.y, ahi.z, ahi.w};
      int4 blo = *(const int4*)&Bs[cb + boff[i]];
      int4 bhi = *(const int4*)&Bs[cb + boff[i] + 512];
      b[i] = (v8i){blo.x, blo.y, blo.z, blo.w, bhi.x, bhi.y, bhi.z, bhi.w};
    }
#pragma unroll
    for (int i = 0; i < 2; ++i)
#pragma unroll
      for (int j = 0; j < 2; ++j)
        acc[i][j] = __builtin_amdgcn_mfma_scale_f32_32x32x64_f8f6f4(
            a[i], b[j], acc[i][j], 0, 0, 0, 127, 0, 127);  // fp8/fp8, scales=2^0

    asm volatile("s_waitcnt lgkmcnt(0)" ::: "memory");
    __builtin_amdgcn_sched_barrier(0);
    __builtin_amdgcn_s_barrier();           // all waves done -> buffer reusable
    cur ^= 1;
  }
#undef STAGE

  // epilogue: 32x32 C/D layout col=l&31, row=(reg&3)+8*(reg>>2)+4*(l>>5) -> bf16
  unsigned short* Pz = P + (size_t)kz * M * Nc;
#pragma unroll
  for (int i = 0; i < 2; ++i) {
#pragma unroll
    for (int j = 0; j < 2; ++j) {
      int colb = n0 + wc + j * 32 + l31;
#pragma unroll
      for (int r = 0; r < 16; ++r) {
        int row = m0 + wr + i * 32 + (r & 3) + 8 * (r >> 2) + 4 * h;
        Pz[(size_t)row * Nc + colb] = f2bf(acc[i][j][r]);
      }
    }
  }
}

// ---- split-K reduce (bf16 partials) + 1/WSC + bias + ReLU -> fp8 image ----
template <int S>
__global__ void reduce_fp8k(const unsigned short* __restrict__ P, const float* __restrict__ bias,
                            unsigned int* __restrict__ outp, long MN4, int nc4) {
  long i = (long)blockIdx.x * blockDim.x + threadIdx.x;
  long stride = (long)gridDim.x * blockDim.x;
  const ushort4* P4 = (const ushort4*)P;
  const float4* B4 = (const float4*)bias;
  for (; i < MN4; i += stride) {
    float vx = 0, vy = 0, vz = 0, vw = 0;
#pragma unroll
    for (int s = 0; s < S; ++s) {
      ushort4 u = P4[s * MN4 + i];
      vx += bf2f(u.x); vy += bf2f(u.y); vz += bf2f(u.z); vw += bf2f(u.w);
    }
    float4 b = B4[i & (nc4 - 1)];
    vx = fmaxf(vx * (1.0f / WSC) + b.x, 0.0f);
    vy = fmaxf(vy * (1.0f / WSC) + b.y, 0.0f);
    vz = fmaxf(vz * (1.0f / WSC) + b.z, 0.0f);
    vw = fmaxf(vw * (1.0f / WSC) + b.w, 0.0f);
    unsigned int r = (unsigned int)__builtin_amdgcn_cvt_pk_fp8_f32(vx, vy, 0, false);
    r = (unsigned int)__builtin_amdgcn_cvt_pk_fp8_f32(vz, vw, (int)r, true);
    // store into tile-image position (row rr, kbyte kb), KT = REPD/64 = 16
    int rr = (int)(i >> 8);
    int kb = ((int)i & 255) * 4;
    outp[img_off(rr, kb, REPD / 64) >> 2] = r;
  }
}

// ---- per-row loss, reading GEMM3's 4 bf16 split-K slices + bias directly ----
__global__ void loss_row(const unsigned short* __restrict__ P, const float* __restrict__ bh,
                         const int* __restrict__ labels, const float* __restrict__ tgts,
                         float* __restrict__ nll_v, float* __restrict__ vc_v,
                         float* __restrict__ sl1_v) {
  int r = blockIdx.x;
  int l = threadIdx.x;
  const size_t SL = (size_t)RT * NH;
  const unsigned short* p0 = P + (size_t)r * NH;
#define COLV(c) ((bf2f(p0[(c)]) + bf2f(p0[SL + (c)]) + bf2f(p0[2 * SL + (c)]) + \
                  bf2f(p0[3 * SL + (c)])) * (1.0f / WSC) + bh[(c)])
  float v1 = COLV(l);
  float v2 = (l < CC - 64) ? COLV(64 + l) : -3.4e38f;
  float m = fmaxf(v1, v2);
#pragma unroll
  for (int o = 32; o; o >>= 1) m = fmaxf(m, __shfl_xor(m, o));
  float e = __expf(v1 - m) + ((l < CC - 64) ? __expf(v2 - m) : 0.0f);
#pragma unroll
  for (int o = 32; o; o >>= 1) e += __shfl_xor(e, o);
  if (l == 0) {
    float lse = m + __logf(e);
    int lab = labels[r];
    int sl = lab < 0 ? 0 : (lab > CC - 1 ? CC - 1 : lab);
    float valid = (lab >= 0) ? 1.0f : 0.0f;
    nll_v[r] = (lse - COLV(sl)) * valid;
    vc_v[r] = valid;
    float s = 0.0f;
#pragma unroll
    for (int d = 0; d < 4; ++d) {
      float pd = COLV(CC + sl * 4 + d);
      float ad = fabsf(pd - tgts[r * 4 + d]);
      s += (ad < BETA) ? 0.5f * ad * ad / BETA : ad - 0.5f * BETA;
    }
    sl1_v[r] = (lab > 0) ? s : 0.0f;
  }
#undef COLV
}

// ---- deterministic final reduce ----
__global__ void reduce_final(const float* __restrict__ nll_v, const float* __restrict__ vc_v,
                             const float* __restrict__ sl1_v, float* __restrict__ out) {
  __shared__ float s1[256], s2[256], s3[256];
  int t = threadIdx.x;
  float a = 0, b = 0, c = 0;
  for (int i = t; i < RT; i += 256) { a += nll_v[i]; b += vc_v[i]; c += sl1_v[i]; }
  s1[t] = a; s2[t] = b; s3[t] = c;
  __syncthreads();
  for (int o = 128; o; o >>= 1) {
    if (t < o) { s1[t] += s1[t + o]; s2[t] += s2[t + o]; s3[t] += s3[t + o]; }
    __syncthreads();
  }
  if (t == 0) {
    out[0] = s1[0] / fmaxf(s2[0], 1.0f);
    out[1] = s3[0] / (float)RT;
  }
}

extern "C" void kernel_launch(void* const* d_in, const int* in_sizes, int n_in,
                              void* d_out, int out_size, void* d_ws, size_t ws_size,
                              hipStream_t stream) {
  const float* proposals = (const float*)d_in[0];
  const float* gt_boxes  = (const float*)d_in[1];
  const float* features  = (const float*)d_in[2];
  const float* W1   = (const float*)d_in[3];
  const float* b1   = (const float*)d_in[4];
  const float* W2   = (const float*)d_in[5];
  const float* b2   = (const float*)d_in[6];
  const float* Wcls = (const float*)d_in[7];
  const float* bcls = (const float*)d_in[8];
  const float* Wbox = (const float*)d_in[9];
  const float* bbox = (const float*)d_in[10];
  const int* gt_labels = (const int*)d_in[11];
  float* out = (float*)d_out;

  char* ws = (char*)d_ws;
  unsigned char* W1t = (unsigned char*)(ws + O_W1T);
  unsigned char* W2t = (unsigned char*)(ws + O_W2T);
  unsigned char* Wh  = (unsigned char*)(ws + O_WH);
  float* bh          = (float*)(ws + O_BH);
  unsigned char* x1  = (unsigned char*)(ws + O_X1);
  unsigned char* x2  = (unsigned char*)(ws + O_X2);
  int* labels        = (int*)(ws + O_LAB);
  float* tgts        = (float*)(ws + O_TGT);
  float* nll_v       = (float*)(ws + O_NLL);
  float* vc_v        = (float*)(ws + O_VC);
  float* sl1_v       = (float*)(ws + O_SL1);
  unsigned short* part = (unsigned short*)(ws + O_PART);
  unsigned char* feat8 = (unsigned char*)(ws + O_F8);

  // 1. prep (SPLIT for attribution): feature image / weight images / misc
  prep_cv<<<NB_CV, 256, 0, stream>>>(features, feat8);
  prep_w<<<NB_PW, 256, 0, stream>>>(W1, W2, Wcls, Wbox, W1t, W2t, Wh);
  prep_misc<<<NB_MISC, 256, 0, stream>>>(bcls, bbox, proposals, gt_boxes, gt_labels,
                                         Wh, bh, labels, tgts);

  // 2. GEMM1: KT=196, split-4 (nkt=49), pairs=33*4=132 -> grid 8*8*17=1088
  gemm_f8<<<1088, 256, 0, stream>>>(feat8, W1t, part, RT, REPD, FEATD/64, 49,
                                    8, 33, 132);
  reduce_fp8k<4><<<2048, 256, 0, stream>>>(part, b1, (unsigned int*)x1,
                                           (long)RT * REPD / 4, REPD / 4);

  // 3. GEMM2: KT=16, split-2 (nkt=8), pairs=66 -> grid 8*8*9=576
  gemm_f8<<<576, 256, 0, stream>>>(x1, W2t, part, RT, REPD, REPD/64, 8,
                                   8, 33, 66);
  reduce_fp8k<2><<<2048, 256, 0, stream>>>(part, b2, (unsigned int*)x2,
                                           (long)RT * REPD / 4, REPD / 4);

  // 4. GEMM3: KT=16, split-4 (nkt=4), Nc=512 (4 n-blocks), pairs=132 -> grid 544
  gemm_f8<<<544, 256, 0, stream>>>(x2, Wh, part, RT, NH, REPD/64, 4,
                                   4, 33, 132);

  // 5. losses (loss_row folds GEMM3's 4-slice reduce + bias + 1/WSC)
  loss_row<<<RT, 64, 0, stream>>>(part, bh, labels, tgts, nll_v, vc_v, sl1_v);
  reduce_final<<<1, 256, 0, stream>>>(nll_v, vc_v, sl1_v, out);
}